// Round 3
// baseline (110.949 us; speedup 1.0000x reference)
//
#include <hip/hip_runtime.h>
#include <math.h>

// FFM_69664369541798 — round 3: full bilinear-form precomputation.
// All 15 cross dots are table-row dot products -> precompute scalar lookup
// tables in d_ws (P1..P4), then a thread-per-row main kernel does ~25 scalar
// gathers + ~40 VALU ops per row.

constexpr int B_ROWS  = 262144;
constexpr int NFEAT   = 45;

// ---- ws layout (float element offsets) ----
constexpr int OFF_CONST = 0;      // [0]=S_lw [1]=b [2]=lw0
constexpr int OFF_LWG   = 8;      // 2
constexpr int OFF_LWO   = 10;     // 21
constexpr int OFF_AG    = 31;     // 2   S*dot(AU,GU[g])
constexpr int OFF_AO    = 33;     // 21  S*dot(AU,OU[o])
constexpr int OFF_GO    = 54;     // 42  S*dot(GU[g],OU[o])
constexpr int OFF_NF    = 96;     // 512  chunk tables: lw24[j]+S*dGM[g][j]
constexpr int OFF_NA    = 608;    // 256  chunk: S*dAM[j]
constexpr int OFF_NO    = 864;    // 5376 chunk: S*dOM[o][j]
constexpr int LDS_TAB   = 864;    // F stages ws[0..864) into LDS
constexpr int OFF_DAM   = 6240;   // 19
constexpr int OFF_DGM   = 6259;   // 38 (raw)
constexpr int OFF_DOM   = 6297;   // 399
constexpr int OFF_PU    = 6696;   // 943*4  {S*dAU,S*dGU0,S*dGU1,user_w}
constexpr int OFF_PT    = 10468;  // 1682*4 {S*dAT,S*dGT0,S*dGT1,item_w}
constexpr int OFF_OU    = 17196;  // 943*21  S*dot(OU[o],UU[u])
constexpr int OFF_OT    = 37000;  // 1682*21 S*dot(OI[o],TU[t])
constexpr int OFF_DMU   = 72324;  // 943*19  S*dot(MU[j],UI[u])
constexpr int OFF_DMT   = 90244;  // 1682*19 S*dot(MI[j],TI[t])
constexpr int OFF_NU    = 122204; // 943*256 chunk of DMU
constexpr int OFF_NT    = 363612; // 1682*256 chunk of DMT
constexpr size_t OFF_UT = 794204; // 943*1682 S*dot(UI[u],TU[t])
constexpr size_t TOT_FLOATS = OFF_UT + (size_t)943 * 1682;   // 2,380,330
constexpr size_t TOT_BYTES  = TOT_FLOATS * 4;

__device__ inline float dot64(const float* __restrict__ a, const float* __restrict__ b) {
    float s = 0.f;
    #pragma unroll
    for (int k = 0; k < 64; k += 4) {
        const float4 av = *reinterpret_cast<const float4*>(a + k);
        const float4 bv = *reinterpret_cast<const float4*>(b + k);
        s += av.x * bv.x + av.y * bv.y + av.z * bv.z + av.w * bv.w;
    }
    return s;
}

// ---- P1: tiny dot tables + consts (one block) ----
__global__ void p1_kernel(const float* __restrict__ AU, const float* __restrict__ AI,
                          const float* __restrict__ GU, const float* __restrict__ GI,
                          const float* __restrict__ OU, const float* __restrict__ OI,
                          const float* __restrict__ MU,
                          const float* __restrict__ lin_w, const float* __restrict__ lin_b,
                          float* __restrict__ ws) {
    float S = 0.f;
    for (int k = 0; k < 43; ++k) S += lin_w[k];
    for (int i = threadIdx.x; i < 545; i += blockDim.x) {
        if (i == 0)       { ws[0] = S; ws[1] = lin_b[0]; ws[2] = lin_w[0]; }
        else if (i < 3)   { ws[OFF_LWG + (i - 1)] = lin_w[i]; }
        else if (i < 24)  { ws[OFF_LWO + (i - 3)] = lin_w[i]; }
        else if (i < 26)  { int g = i - 24; ws[OFF_AG + g] = S * dot64(AU, GU + g * 64); }
        else if (i < 47)  { int o = i - 26; ws[OFF_AO + o] = S * dot64(AU, OU + o * 64); }
        else if (i < 89)  { int j = i - 47; ws[OFF_GO + j] = S * dot64(GU + (j / 21) * 64, OU + (j % 21) * 64); }
        else if (i < 108) { int j = i - 89; ws[OFF_DAM + j] = S * dot64(AI, MU + j * 64); }
        else if (i < 146) { int j = i - 108; ws[OFF_DGM + j] = dot64(GI + (j / 19) * 64, MU + (j % 19) * 64); }
        else              { int j = i - 146; ws[OFF_DOM + j] = S * dot64(OI + (j / 19) * 64, MU + (j % 19) * 64); }
    }
}

// ---- P2: per-uid/iid dot tables (thread-per-output) ----
constexpr int P2_JOBS = 943 + 1682 + 943 * 21 + 1682 * 21 + 943 * 19 + 1682 * 19; // 107625
__global__ __launch_bounds__(256) void p2_kernel(
    const float* __restrict__ AU, const float* __restrict__ AI,
    const float* __restrict__ GU, const float* __restrict__ GI,
    const float* __restrict__ OU, const float* __restrict__ OI,
    const float* __restrict__ MU, const float* __restrict__ MI,
    const float* __restrict__ UU, const float* __restrict__ UI,
    const float* __restrict__ TU, const float* __restrict__ TI,
    const float* __restrict__ user_w, const float* __restrict__ item_w,
    float* __restrict__ ws) {
    int j = blockIdx.x * 256 + threadIdx.x;
    if (j >= P2_JOBS) return;
    const float S = ws[0];
    if (j < 943) {
        float4 v;
        v.x = S * dot64(AU, UU + j * 64);
        v.y = S * dot64(GU, UU + j * 64);
        v.z = S * dot64(GU + 64, UU + j * 64);
        v.w = user_w[j];
        *reinterpret_cast<float4*>(ws + OFF_PU + 4 * j) = v;
        return;
    }
    j -= 943;
    if (j < 1682) {
        float4 v;
        v.x = S * dot64(AI, TU + j * 64);
        v.y = S * dot64(GI, TU + j * 64);
        v.z = S * dot64(GI + 64, TU + j * 64);
        v.w = item_w[j];
        *reinterpret_cast<float4*>(ws + OFF_PT + 4 * j) = v;
        return;
    }
    j -= 1682;
    if (j < 943 * 21) {
        int u = j / 21, o = j % 21;
        ws[OFF_OU + j] = S * dot64(OU + o * 64, UU + u * 64);
        return;
    }
    j -= 943 * 21;
    if (j < 1682 * 21) {
        int t = j / 21, o = j % 21;
        ws[OFF_OT + j] = S * dot64(OI + o * 64, TU + t * 64);
        return;
    }
    j -= 1682 * 21;
    if (j < 943 * 19) {
        int u = j / 19, m = j % 19;
        ws[OFF_DMU + j] = S * dot64(MU + m * 64, UI + u * 64);
        return;
    }
    j -= 943 * 19;
    {
        int t = j / 19, m = j % 19;
        ws[OFF_DMT + j] = S * dot64(MI + m * 64, TI + t * 64);
    }
}

// ---- P3: UT[u][t] = S*dot(UI[u], TU[t])  (943x1682, thread-per-output) ----
__global__ __launch_bounds__(256) void p3_kernel(const float* __restrict__ UI,
                                                 const float* __restrict__ TU,
                                                 float* __restrict__ ws) {
    const int u = blockIdx.x * 16 + (threadIdx.x >> 4);
    const int t = blockIdx.y * 16 + (threadIdx.x & 15);
    if (u < 943 && t < 1682) {
        const float S = ws[0];
        ws[OFF_UT + (size_t)u * 1682 + t] = S * dot64(UI + u * 64, TU + t * 64);
    }
}

// ---- P4: movie-mask chunk tables (19 bits = 7+6+6) ----
constexpr int P4_JOBS = 512 + 256 + 21 * 256 + 943 * 256 + 1682 * 256; // 678144
__global__ __launch_bounds__(256) void p4_kernel(const float* __restrict__ lin_w,
                                                 float* __restrict__ ws) {
    int idx = blockIdx.x * 256 + threadIdx.x;
    if (idx >= P4_JOBS) return;
    const float S = ws[0];
    int table, row, e;
    if (idx < 512)          { table = 0; row = idx >> 8; e = idx & 255; }
    else if (idx < 768)     { table = 1; row = 0; e = idx - 512; }
    else if (idx < 6144)    { int q = idx - 768;    table = 2; row = q >> 8; e = q & 255; }
    else if (idx < 247552)  { int q = idx - 6144;   table = 3; row = q >> 8; e = q & 255; }
    else                    { int q = idx - 247552; table = 4; row = q >> 8; e = q & 255; }
    const int c  = (e < 128) ? 0 : ((e < 192) ? 1 : 2);
    const int s  = e - ((c == 0) ? 0 : ((c == 1) ? 128 : 192));
    const int j0 = (c == 0) ? 0 : ((c == 1) ? 7 : 13);
    const int L  = (c == 0) ? 7 : 6;
    float v = 0.f;
    for (int b = 0; b < L; ++b) {
        if ((s >> b) & 1) {
            const int j = j0 + b;
            float x;
            if (table == 0)      x = lin_w[24 + j] + S * ws[OFF_DGM + row * 19 + j];
            else if (table == 1) x = ws[OFF_DAM + j];
            else if (table == 2) x = ws[OFF_DOM + row * 19 + j];
            else if (table == 3) x = ws[OFF_DMU + row * 19 + j];
            else                 x = ws[OFF_DMT + row * 19 + j];
            v += x;
        }
    }
    int dst;
    if (table == 0)      dst = OFF_NF + row * 256 + e;
    else if (table == 1) dst = OFF_NA + e;
    else if (table == 2) dst = OFF_NO + row * 256 + e;
    else if (table == 3) dst = OFF_NU + row * 256 + e;
    else                 dst = OFF_NT + row * 256 + e;
    ws[dst] = v;
}

// ---- F: main thread-per-row kernel ----
__global__ __launch_bounds__(256) void ffm_main(const float* __restrict__ fv,
                                                const float* __restrict__ ws,
                                                float* __restrict__ out) {
    __shared__ float T[LDS_TAB];
    __shared__ __align__(16) float SF[4][64 * NFEAT];
    const int tid  = threadIdx.x;
    const int lane = tid & 63;
    const int wid  = tid >> 6;
    for (int i = tid; i < LDS_TAB; i += 256) T[i] = ws[i];

    const int row0 = blockIdx.x * 256;
    // stage this wave's 64 rows (11520 B) coalesced
    {
        const float* src = fv + (size_t)(row0 + wid * 64) * NFEAT;
        float* sf = SF[wid];
        #pragma unroll
        for (int i = 0; i < 11; ++i) {
            const int s4 = i * 64 + lane;
            *reinterpret_cast<float4*>(sf + s4 * 4) =
                *reinterpret_cast<const float4*>(src + s4 * 4);
        }
        sf[2816 + lane] = src[2816 + lane];
    }
    __syncthreads();

    const float* f = SF[wid] + lane * NFEAT;
    const int   uid = (int)f[0];
    const int   iid = (int)f[1];
    const float age = f[2];
    const int   g   = (f[4] > 0.5f) ? 1 : 0;
    float oacc = 0.f, macc = 0.f;
    #pragma unroll
    for (int k = 1; k < 21; ++k) oacc += f[5 + k] * (float)k;     // one-hot -> index
    const int o = (int)oacc;
    #pragma unroll
    for (int j = 0; j < 19; ++j) macc += f[26 + j] * (float)(1u << j); // exact < 2^24
    const unsigned m  = (unsigned)macc;
    const unsigned c0 = m & 127u, c1 = (m >> 7) & 63u, c2 = m >> 13;

    const float4 pu = *reinterpret_cast<const float4*>(ws + OFF_PU + 4 * uid);
    const float4 pt = *reinterpret_cast<const float4*>(ws + OFF_PT + 4 * iid);
    const float ouv = ws[OFF_OU + uid * 21 + o];
    const float otv = ws[OFF_OT + iid * 21 + o];
    const float utv = ws[OFF_UT + (size_t)uid * 1682 + iid];
    const float* nu = ws + OFF_NU + uid * 256;
    const float nuv = nu[c0] + nu[128 + c1] + nu[192 + c2];
    const float* nt = ws + OFF_NT + iid * 256;
    const float ntv = nt[c0] + nt[128 + c1] + nt[192 + c2];
    const float* no = ws + OFF_NO + o * 256;
    const float nov = no[c0] + no[128 + c1] + no[192 + c2];
    const float* nf = T + OFF_NF + g * 256;
    const float nfv = nf[c0] + nf[128 + c1] + nf[192 + c2];
    const float* na = T + OFF_NA;
    const float nav = na[c0] + na[128 + c1] + na[192 + c2];

    const float total =
          pu.w + pt.w + T[1]                                   // user_w + item_w + b
        + age * T[2] + T[OFF_LWG + g] + T[OFF_LWO + o]         // lin: age,g,o
        + age * (T[OFF_AG + g] + T[OFF_AO + o] + pu.x + pt.x)  // au·gu,au·ou,au·uu,ai·tu
        + (g ? pu.z : pu.y) + (g ? pt.z : pt.y)                // gu·uu, gi·tu
        + T[OFF_GO + g * 21 + o] + ouv + otv + utv             // gu·ou, ou·uu, oi·tu, ui·tu
        + nfv + age * nav + nov + nuv + ntv;                   // movie streams (+ lin movie)

    out[row0 + wid * 64 + lane] = 1.f / (1.f + __expf(-total));
}

// ---- fallback (round-2 kernel) if ws is too small ----
constexpr int RPW = 16, THREADS = 256, WPB = 4, FPW = RPW * NFEAT;
__global__ __launch_bounds__(THREADS) void ffm_fallback(
    const float* __restrict__ fv,
    const float* __restrict__ AU, const float* __restrict__ AI,
    const float* __restrict__ GU, const float* __restrict__ GI,
    const float* __restrict__ OU, const float* __restrict__ OI,
    const float* __restrict__ MU, const float* __restrict__ MI,
    const float* __restrict__ UU, const float* __restrict__ UI,
    const float* __restrict__ TU, const float* __restrict__ TI,
    const float* __restrict__ user_w, const float* __restrict__ item_w,
    const float* __restrict__ lin_w, const float* __restrict__ lin_b,
    float* __restrict__ out)
{
    __shared__ __align__(16) float stage[WPB][FPW];
    const int lane = threadIdx.x & 63;
    const int wid  = threadIdx.x >> 6;
    const int waveId = blockIdx.x * WPB + wid;
    const int rowBase = waveId * RPW;
    {
        const float* src = fv + (size_t)rowBase * NFEAT;
        float* dst = stage[wid];
        #pragma unroll
        for (int t = 0; t < 3; ++t) {
            const int idx = t * 64 + lane;
            if (idx < FPW / 4)
                *reinterpret_cast<float4*>(dst + idx * 4) =
                    *reinterpret_cast<const float4*>(src + idx * 4);
        }
    }
    const float* S = stage[wid];
    const float au_w = AU[lane], ai_w = AI[lane];
    const float gu0 = GU[lane], gu1 = GU[64 + lane];
    const float gi0 = GI[lane], gi1 = GI[64 + lane];
    const float lw = (lane >= 2 && lane < NFEAT) ? lin_w[lane - 2] : 0.0f;
    const float bias = lin_b[0];
    float sum_lin = lw;
    #pragma unroll
    for (int off = 32; off; off >>= 1) sum_lin += __shfl_xor(sum_lin, off);
    float myval = 0.0f;
    for (int r = 0; r < RPW; ++r) {
        const float* rp = S + r * NFEAT;
        const float x = (lane < NFEAT) ? rp[lane] : 0.0f;
        const int uid = (int)rp[0], iid = (int)rp[1];
        const float age = rp[2], g0 = rp[3], g1 = rp[4];
        const unsigned long long ball = __ballot(x != 0.0f);
        const unsigned occm = (unsigned)((ball >> 5) & 0x1FFFFFull);
        unsigned movm = (unsigned)((ball >> 26) & 0x7FFFFull);
        const float au = age * au_w, ai = age * ai_w;
        const float gu = g0 * gu0 + g1 * gu1, gi = g0 * gi0 + g1 * gi1;
        float ou = 0.0f, oi = 0.0f;
        if (occm) { const int j = __builtin_ctz(occm); ou = OU[j * 64 + lane]; oi = OI[j * 64 + lane]; }
        float mu = 0.0f, mi = 0.0f;
        while (movm) { const int j = __builtin_ctz(movm); movm &= movm - 1; mu += MU[j * 64 + lane]; mi += MI[j * 64 + lane]; }
        const float uu = UU[uid * 64 + lane], ui_ = UI[uid * 64 + lane];
        const float tu = TU[iid * 64 + lane], ti = TI[iid * 64 + lane];
        const float part = (ai + gi + oi) * (mu + tu) + au * (gu + ou + uu)
                         + gu * (ou + uu) + ou * uu + mu * ui_ + mi * ti + ui_ * tu;
        float red = part * sum_lin + x * lw;
        #pragma unroll
        for (int off = 32; off; off >>= 1) red += __shfl_xor(red, off);
        const float val = user_w[uid] + item_w[iid] + bias + red;
        if (lane == r) myval = val;
    }
    if (lane < RPW) out[rowBase + lane] = 1.0f / (1.0f + __expf(-myval));
}

extern "C" void kernel_launch(void* const* d_in, const int* in_sizes, int n_in,
                              void* d_out, int out_size, void* d_ws, size_t ws_size,
                              hipStream_t stream) {
    const float* fv = (const float*)d_in[0];
    const float* AU = (const float*)d_in[1];
    const float* AI = (const float*)d_in[2];
    const float* GU = (const float*)d_in[3];
    const float* GI = (const float*)d_in[4];
    const float* OU = (const float*)d_in[5];
    const float* OI = (const float*)d_in[6];
    const float* MU = (const float*)d_in[7];
    const float* MI = (const float*)d_in[8];
    const float* UU = (const float*)d_in[9];
    const float* UI = (const float*)d_in[10];
    const float* TU = (const float*)d_in[11];
    const float* TI = (const float*)d_in[12];
    const float* uw = (const float*)d_in[13];
    const float* iw = (const float*)d_in[14];
    const float* lw = (const float*)d_in[15];
    const float* lb = (const float*)d_in[16];
    float* out = (float*)d_out;
    float* ws  = (float*)d_ws;

    if (ws_size < TOT_BYTES) {
        ffm_fallback<<<B_ROWS / RPW / WPB, THREADS, 0, stream>>>(
            fv, AU, AI, GU, GI, OU, OI, MU, MI, UU, UI, TU, TI, uw, iw, lw, lb, out);
        return;
    }

    p1_kernel<<<1, 256, 0, stream>>>(AU, AI, GU, GI, OU, OI, MU, lw, lb, ws);
    p2_kernel<<<(P2_JOBS + 255) / 256, 256, 0, stream>>>(
        AU, AI, GU, GI, OU, OI, MU, MI, UU, UI, TU, TI, uw, iw, ws);
    p3_kernel<<<dim3((943 + 15) / 16, (1682 + 15) / 16), 256, 0, stream>>>(UI, TU, ws);
    p4_kernel<<<(P4_JOBS + 255) / 256, 256, 0, stream>>>(lw, ws);
    ffm_main<<<B_ROWS / 256, 256, 0, stream>>>(fv, ws, out);
}

// Round 4
// 88.837 us; speedup vs baseline: 1.2489x; 1.2489x over previous
//
#include <hip/hip_runtime.h>
#include <math.h>

// FFM_69664369541798 — round 4: bilinear precompute, now with a real tiled
// GEMM (K2) + chunk-basis factorization (kills old P3/P4 latency disease).
// K1: consts + chunk-basis vectors + copies (1 block)
// K2: generic tiled GEMM C = S*A(R,64)@B(N,64)^T over 6 segments
// F : thread-per-row scoring (scalar gathers only)

constexpr int B_ROWS = 262144;
constexpr int NFEAT  = 45;

// ---- ws layout (float offsets) ----
constexpr int OFF_LWG = 8;      // 2
constexpr int OFF_LWO = 10;     // 21
constexpr int OFF_AG  = 31;     // 2
constexpr int OFF_AO  = 33;     // 21
constexpr int OFF_GO  = 54;     // 42 -> 96
constexpr int OFF_LWC = 96;     // 256 lwchunk
constexpr int OFF_CMU = 352;    // 256*64
constexpr int OFF_CMI = 16736;  // 256*64
constexpr int OFF_BU  = 33120;  // 27*64
constexpr int OFF_BT  = 34848;  // 27*64
constexpr int OFF_ASM = 36576;  // 24*64
constexpr int OFF_NO  = 38112;  // 21*256
constexpr int OFF_NF  = 43488;  // 2*256   (contiguous after NO: rows 21,22)
constexpr int OFF_NA  = 44000;  // 256     (row 23)
constexpr int OFF_PUO = 44256;  // 943*28  [0..20]=OU dots, 24..27={au,gu0,gu1,user_w}
constexpr int OFF_PTO = 70660;  // 1682*28
constexpr int OFF_NU  = 117756; // 943*256
constexpr int OFF_NT  = 359164; // 1682*256
constexpr size_t OFF_UT = 789756; // 943*1682
constexpr size_t TOT_FLOATS = OFF_UT + (size_t)943 * 1682; // 2,375,882
constexpr size_t TOT_BYTES  = TOT_FLOATS * 4;

__device__ inline float dot64(const float* __restrict__ a, const float* __restrict__ b) {
    float s = 0.f;
    #pragma unroll
    for (int k = 0; k < 64; k += 4) {
        const float4 av = *reinterpret_cast<const float4*>(a + k);
        const float4 bv = *reinterpret_cast<const float4*>(b + k);
        s += av.x * bv.x + av.y * bv.y + av.z * bv.z + av.w * bv.w;
    }
    return s;
}

// ---- K1: setup (one block, 256 threads) ----
__global__ __launch_bounds__(256) void k1_setup(
    const float* __restrict__ AU, const float* __restrict__ AI,
    const float* __restrict__ GU, const float* __restrict__ GI,
    const float* __restrict__ OU, const float* __restrict__ OI,
    const float* __restrict__ MU, const float* __restrict__ MI,
    const float* __restrict__ user_w, const float* __restrict__ item_w,
    const float* __restrict__ lin_w, const float* __restrict__ lin_b,
    float* __restrict__ ws)
{
    const int tid = threadIdx.x;
    float S = 0.f;
    for (int k = 0; k < 43; ++k) S += lin_w[k];

    if (tid == 0)       { ws[0] = S; ws[1] = lin_b[0]; ws[2] = lin_w[0]; }
    else if (tid < 3)   { ws[OFF_LWG + tid - 1] = lin_w[tid]; }
    else if (tid < 24)  { ws[OFF_LWO + tid - 3] = lin_w[tid]; }
    else if (tid < 26)  { int g = tid - 24; ws[OFF_AG + g] = S * dot64(AU, GU + g * 64); }
    else if (tid < 47)  { int o = tid - 26; ws[OFF_AO + o] = S * dot64(AU, OU + o * 64); }
    else if (tid < 89)  { int j = tid - 47; ws[OFF_GO + j] = S * dot64(GU + (j / 21) * 64, OU + (j % 21) * 64); }

    // chunk-basis vectors + lwchunk (e = tid)
    {
        const int e = tid;
        int j0, L, s;
        if (e < 128)      { j0 = 0;  L = 7; s = e; }
        else if (e < 192) { j0 = 7;  L = 6; s = e - 128; }
        else              { j0 = 13; L = 6; s = e - 192; }
        float lc = 0.f;
        for (int b = 0; b < L; ++b) if ((s >> b) & 1) lc += lin_w[24 + j0 + b];
        ws[OFF_LWC + e] = lc;
        for (int k4 = 0; k4 < 16; ++k4) {
            float4 su = make_float4(0.f, 0.f, 0.f, 0.f);
            float4 si = make_float4(0.f, 0.f, 0.f, 0.f);
            for (int b = 0; b < L; ++b) if ((s >> b) & 1) {
                const float4 mu = *reinterpret_cast<const float4*>(MU + (j0 + b) * 64 + k4 * 4);
                const float4 mi = *reinterpret_cast<const float4*>(MI + (j0 + b) * 64 + k4 * 4);
                su.x += mu.x; su.y += mu.y; su.z += mu.z; su.w += mu.w;
                si.x += mi.x; si.y += mi.y; si.z += mi.z; si.w += mi.w;
            }
            *reinterpret_cast<float4*>(ws + OFF_CMU + e * 64 + k4 * 4) = su;
            *reinterpret_cast<float4*>(ws + OFF_CMI + e * 64 + k4 * 4) = si;
        }
    }

    // BU = [OU(21); 0,0,0; AU; GU0; GU1]   (27 x 64)
    for (int i = tid; i < 27 * 64; i += 256) {
        const int r = i >> 6, c = i & 63;
        float v;
        if (r < 21)      v = OU[r * 64 + c];
        else if (r < 24) v = 0.f;
        else if (r == 24) v = AU[c];
        else              v = GU[(r - 25) * 64 + c];
        ws[OFF_BU + i] = v;
    }
    // BT = [OI(21); 0,0,0; AI; GI0; GI1]
    for (int i = tid; i < 27 * 64; i += 256) {
        const int r = i >> 6, c = i & 63;
        float v;
        if (r < 21)      v = OI[r * 64 + c];
        else if (r < 24) v = 0.f;
        else if (r == 24) v = AI[c];
        else              v = GI[(r - 25) * 64 + c];
        ws[OFF_BT + i] = v;
    }
    // ASM = [OI(21); GI0; GI1; AI]   (24 x 64)  — rows 21,22 get +lwchunk in K2
    for (int i = tid; i < 24 * 64; i += 256) {
        const int r = i >> 6, c = i & 63;
        float v;
        if (r < 21)      v = OI[r * 64 + c];
        else if (r < 23) v = GI[(r - 21) * 64 + c];
        else             v = AI[c];
        ws[OFF_ASM + i] = v;
    }
    for (int i = tid; i < 943;  i += 256) ws[OFF_PUO + i * 28 + 27] = user_w[i];
    for (int i = tid; i < 1682; i += 256) ws[OFF_PTO + i * 28 + 27] = item_w[i];
}

// ---- K2: generic tiled GEMM  C[r][c] = S * dot(A[r], B[c]) (+lwchunk) ----
// segments: UT(405) NU(60) NT(108) OUPU(15) OTPT(27) SMALL(4) = 619 blocks
constexpr int K2_BLOCKS = 405 + 60 + 108 + 15 + 27 + 4;

__global__ __launch_bounds__(256) void k2_gemm(
    const float* __restrict__ UI, const float* __restrict__ TI,
    const float* __restrict__ UU, const float* __restrict__ TU,
    float* __restrict__ ws)
{
    __shared__ __align__(16) float As[64][68];  // transposed: As[k][row]
    __shared__ __align__(16) float Bs[64][68];  // Bs[k][col]

    int b = blockIdx.x;
    const float* Ap; const float* Bp; float* Cp;
    int AR, BR, CS, r0, c0; bool alw = false;
    if (b < 405)              { Ap = UI; AR = 943;  Bp = TU;           BR = 1682; Cp = ws + OFF_UT;  CS = 1682; r0 = (b / 27) * 64; c0 = (b % 27) * 64; }
    else if ((b -= 405) < 60) { Ap = UI; AR = 943;  Bp = ws + OFF_CMU; BR = 256;  Cp = ws + OFF_NU;  CS = 256;  r0 = (b / 4) * 64;  c0 = (b % 4) * 64; }
    else if ((b -= 60) < 108) { Ap = TI; AR = 1682; Bp = ws + OFF_CMI; BR = 256;  Cp = ws + OFF_NT;  CS = 256;  r0 = (b / 4) * 64;  c0 = (b % 4) * 64; }
    else if ((b -= 108) < 15) { Ap = UU; AR = 943;  Bp = ws + OFF_BU;  BR = 27;   Cp = ws + OFF_PUO; CS = 28;   r0 = b * 64;        c0 = 0; }
    else if ((b -= 15) < 27)  { Ap = TU; AR = 1682; Bp = ws + OFF_BT;  BR = 27;   Cp = ws + OFF_PTO; CS = 28;   r0 = b * 64;        c0 = 0; }
    else { b -= 27;             Ap = ws + OFF_ASM; AR = 24; Bp = ws + OFF_CMU; BR = 256; Cp = ws + OFF_NO; CS = 256; r0 = 0; c0 = b * 64; alw = true; }

    const float S = ws[0];
    const int tid = threadIdx.x;

    #pragma unroll
    for (int i = 0; i < 4; ++i) {
        const int q  = tid + i * 256;      // 0..1023
        const int r  = q >> 4;             // 0..63
        const int c4 = (q & 15) * 4;
        float4 va = make_float4(0.f, 0.f, 0.f, 0.f);
        if (r0 + r < AR) va = *reinterpret_cast<const float4*>(Ap + (size_t)(r0 + r) * 64 + c4);
        As[c4 + 0][r] = va.x; As[c4 + 1][r] = va.y; As[c4 + 2][r] = va.z; As[c4 + 3][r] = va.w;
        float4 vb = make_float4(0.f, 0.f, 0.f, 0.f);
        if (c0 + r < BR) vb = *reinterpret_cast<const float4*>(Bp + (size_t)(c0 + r) * 64 + c4);
        Bs[c4 + 0][r] = vb.x; Bs[c4 + 1][r] = vb.y; Bs[c4 + 2][r] = vb.z; Bs[c4 + 3][r] = vb.w;
    }
    __syncthreads();

    const int tx = tid & 15, ty = tid >> 4;
    float acc[4][4] = {};
    #pragma unroll 8
    for (int k = 0; k < 64; ++k) {
        const float4 a = *reinterpret_cast<const float4*>(&As[k][ty * 4]);
        const float4 bv = *reinterpret_cast<const float4*>(&Bs[k][tx * 4]);
        const float av[4] = {a.x, a.y, a.z, a.w};
        const float bw[4] = {bv.x, bv.y, bv.z, bv.w};
        #pragma unroll
        for (int i = 0; i < 4; ++i)
            #pragma unroll
            for (int j = 0; j < 4; ++j)
                acc[i][j] += av[i] * bw[j];
    }

    #pragma unroll
    for (int i = 0; i < 4; ++i) {
        const int gr = r0 + ty * 4 + i;
        if (gr >= AR) continue;
        #pragma unroll
        for (int j = 0; j < 4; ++j) {
            const int gc = c0 + tx * 4 + j;
            if (gc >= BR) continue;
            float v = S * acc[i][j];
            if (alw && (gr == 21 || gr == 22)) v += ws[OFF_LWC + gc];
            Cp[(size_t)gr * CS + gc] = v;
        }
    }
}

// ---- F: main thread-per-row kernel ----
__global__ __launch_bounds__(256) void ffm_main(const float* __restrict__ fv,
                                                const float* __restrict__ ws,
                                                float* __restrict__ out) {
    __shared__ float T[864];                       // consts(96) NF(512) NA(256)
    __shared__ __align__(16) float SF[4][64 * NFEAT];
    const int tid  = threadIdx.x;
    const int lane = tid & 63;
    const int wid  = tid >> 6;
    for (int i = tid; i < 96;  i += 256) T[i]       = ws[i];
    for (int i = tid; i < 512; i += 256) T[96 + i]  = ws[OFF_NF + i];
    for (int i = tid; i < 256; i += 256) T[608 + i] = ws[OFF_NA + i];

    const int row0 = blockIdx.x * 256;
    {
        const float* src = fv + (size_t)(row0 + wid * 64) * NFEAT;
        float* sf = SF[wid];
        #pragma unroll
        for (int i = 0; i < 11; ++i) {
            const int s4 = i * 64 + lane;
            *reinterpret_cast<float4*>(sf + s4 * 4) =
                *reinterpret_cast<const float4*>(src + s4 * 4);
        }
        sf[2816 + lane] = src[2816 + lane];
    }
    __syncthreads();

    const float* f = SF[wid] + lane * NFEAT;
    const int   uid = (int)f[0];
    const int   iid = (int)f[1];
    const float age = f[2];
    const int   g   = (f[4] > 0.5f) ? 1 : 0;
    float oacc = 0.f, macc = 0.f;
    #pragma unroll
    for (int k = 1; k < 21; ++k) oacc += f[5 + k] * (float)k;
    const int o = (int)oacc;
    #pragma unroll
    for (int j = 0; j < 19; ++j) macc += f[26 + j] * (float)(1u << j);
    const unsigned m  = (unsigned)macc;
    const unsigned c0 = m & 127u, c1 = (m >> 7) & 63u, c2 = m >> 13;

    const float* pu = ws + OFF_PUO + uid * 28;
    const float* pt = ws + OFF_PTO + iid * 28;
    const float4 puq = *reinterpret_cast<const float4*>(pu + 24); // {au,gu0,gu1,user_w}
    const float4 ptq = *reinterpret_cast<const float4*>(pt + 24); // {ai,gi0,gi1,item_w}
    const float ouv = pu[o];
    const float otv = pt[o];
    const float utv = ws[OFF_UT + (size_t)uid * 1682 + iid];
    const float* nu = ws + OFF_NU + uid * 256;
    const float nuv = nu[c0] + nu[128 + c1] + nu[192 + c2];
    const float* nt = ws + OFF_NT + iid * 256;
    const float ntv = nt[c0] + nt[128 + c1] + nt[192 + c2];
    const float* no = ws + OFF_NO + o * 256;
    const float nov = no[c0] + no[128 + c1] + no[192 + c2];
    const float* nf = T + 96 + g * 256;
    const float nfv = nf[c0] + nf[128 + c1] + nf[192 + c2];
    const float* na = T + 608;
    const float nav = na[c0] + na[128 + c1] + na[192 + c2];

    const float total =
          puq.w + ptq.w + T[1]
        + age * T[2] + T[OFF_LWG + g] + T[OFF_LWO + o]
        + age * (T[OFF_AG + g] + T[OFF_AO + o] + puq.x + ptq.x)
        + (g ? puq.z : puq.y) + (g ? ptq.z : ptq.y)
        + T[OFF_GO + g * 21 + o] + ouv + otv + utv
        + nfv + age * nav + nov + nuv + ntv;

    out[row0 + wid * 64 + lane] = 1.f / (1.f + __expf(-total));
}

// ---- fallback (round-2 kernel) if ws is too small ----
constexpr int RPW = 16, THREADS = 256, WPB = 4, FPW = RPW * NFEAT;
__global__ __launch_bounds__(THREADS) void ffm_fallback(
    const float* __restrict__ fv,
    const float* __restrict__ AU, const float* __restrict__ AI,
    const float* __restrict__ GU, const float* __restrict__ GI,
    const float* __restrict__ OU, const float* __restrict__ OI,
    const float* __restrict__ MU, const float* __restrict__ MI,
    const float* __restrict__ UU, const float* __restrict__ UI,
    const float* __restrict__ TU, const float* __restrict__ TI,
    const float* __restrict__ user_w, const float* __restrict__ item_w,
    const float* __restrict__ lin_w, const float* __restrict__ lin_b,
    float* __restrict__ out)
{
    __shared__ __align__(16) float stage[WPB][FPW];
    const int lane = threadIdx.x & 63;
    const int wid  = threadIdx.x >> 6;
    const int rowBase = (blockIdx.x * WPB + wid) * RPW;
    {
        const float* src = fv + (size_t)rowBase * NFEAT;
        float* dst = stage[wid];
        #pragma unroll
        for (int t = 0; t < 3; ++t) {
            const int idx = t * 64 + lane;
            if (idx < FPW / 4)
                *reinterpret_cast<float4*>(dst + idx * 4) =
                    *reinterpret_cast<const float4*>(src + idx * 4);
        }
    }
    const float* Srow = stage[wid];
    const float au_w = AU[lane], ai_w = AI[lane];
    const float gu0 = GU[lane], gu1 = GU[64 + lane];
    const float gi0 = GI[lane], gi1 = GI[64 + lane];
    const float lw = (lane >= 2 && lane < NFEAT) ? lin_w[lane - 2] : 0.0f;
    const float bias = lin_b[0];
    float sum_lin = lw;
    #pragma unroll
    for (int off = 32; off; off >>= 1) sum_lin += __shfl_xor(sum_lin, off);
    float myval = 0.0f;
    for (int r = 0; r < RPW; ++r) {
        const float* rp = Srow + r * NFEAT;
        const float x = (lane < NFEAT) ? rp[lane] : 0.0f;
        const int uid = (int)rp[0], iid = (int)rp[1];
        const float age = rp[2], g0 = rp[3], g1 = rp[4];
        const unsigned long long ball = __ballot(x != 0.0f);
        const unsigned occm = (unsigned)((ball >> 5) & 0x1FFFFFull);
        unsigned movm = (unsigned)((ball >> 26) & 0x7FFFFull);
        const float au = age * au_w, ai = age * ai_w;
        const float gu = g0 * gu0 + g1 * gu1, gi = g0 * gi0 + g1 * gi1;
        float ou = 0.0f, oi = 0.0f;
        if (occm) { const int j = __builtin_ctz(occm); ou = OU[j * 64 + lane]; oi = OI[j * 64 + lane]; }
        float mu = 0.0f, mi = 0.0f;
        while (movm) { const int j = __builtin_ctz(movm); movm &= movm - 1; mu += MU[j * 64 + lane]; mi += MI[j * 64 + lane]; }
        const float uu = UU[uid * 64 + lane], ui_ = UI[uid * 64 + lane];
        const float tu = TU[iid * 64 + lane], ti = TI[iid * 64 + lane];
        const float part = (ai + gi + oi) * (mu + tu) + au * (gu + ou + uu)
                         + gu * (ou + uu) + ou * uu + mu * ui_ + mi * ti + ui_ * tu;
        float red = part * sum_lin + x * lw;
        #pragma unroll
        for (int off = 32; off; off >>= 1) red += __shfl_xor(red, off);
        const float val = user_w[uid] + item_w[iid] + bias + red;
        if (lane == r) myval = val;
    }
    if (lane < RPW) out[rowBase + lane] = 1.0f / (1.0f + __expf(-myval));
}

extern "C" void kernel_launch(void* const* d_in, const int* in_sizes, int n_in,
                              void* d_out, int out_size, void* d_ws, size_t ws_size,
                              hipStream_t stream) {
    const float* fv = (const float*)d_in[0];
    const float* AU = (const float*)d_in[1];
    const float* AI = (const float*)d_in[2];
    const float* GU = (const float*)d_in[3];
    const float* GI = (const float*)d_in[4];
    const float* OU = (const float*)d_in[5];
    const float* OI = (const float*)d_in[6];
    const float* MU = (const float*)d_in[7];
    const float* MI = (const float*)d_in[8];
    const float* UU = (const float*)d_in[9];
    const float* UI = (const float*)d_in[10];
    const float* TU = (const float*)d_in[11];
    const float* TI = (const float*)d_in[12];
    const float* uw = (const float*)d_in[13];
    const float* iw = (const float*)d_in[14];
    const float* lw = (const float*)d_in[15];
    const float* lb = (const float*)d_in[16];
    float* out = (float*)d_out;
    float* ws  = (float*)d_ws;

    if (ws_size < TOT_BYTES) {
        ffm_fallback<<<B_ROWS / RPW / WPB, THREADS, 0, stream>>>(
            fv, AU, AI, GU, GI, OU, OI, MU, MI, UU, UI, TU, TI, uw, iw, lw, lb, out);
        return;
    }

    k1_setup<<<1, 256, 0, stream>>>(AU, AI, GU, GI, OU, OI, MU, MI, uw, iw, lw, lb, ws);
    k2_gemm<<<K2_BLOCKS, 256, 0, stream>>>(UI, TI, UU, TU, ws);
    ffm_main<<<B_ROWS / 256, 256, 0, stream>>>(fv, ws, out);
}

// Round 5
// 49.530 us; speedup vs baseline: 2.2400x; 1.7936x over previous
//
#include <hip/hip_runtime.h>
#include <math.h>

// FFM_69664369541798 — round 5: parallelize K1 (was 1 block = 46 us latency
// disease). K2 tiled GEMM + F scoring unchanged from round 4.

constexpr int B_ROWS = 262144;
constexpr int NFEAT  = 45;

// ---- ws layout (float offsets) ----
constexpr int OFF_LWG = 8;      // 2
constexpr int OFF_LWO = 10;     // 21
constexpr int OFF_AG  = 31;     // 2
constexpr int OFF_AO  = 33;     // 21
constexpr int OFF_GO  = 54;     // 42 -> 96
constexpr int OFF_LWC = 96;     // 256 lwchunk
constexpr int OFF_CMU = 352;    // 256*64
constexpr int OFF_CMI = 16736;  // 256*64
constexpr int OFF_BU  = 33120;  // 27*64
constexpr int OFF_BT  = 34848;  // 27*64
constexpr int OFF_ASM = 36576;  // 24*64
constexpr int OFF_NO  = 38112;  // 21*256
constexpr int OFF_NF  = 43488;  // 2*256
constexpr int OFF_NA  = 44000;  // 256
constexpr int OFF_PUO = 44256;  // 943*28
constexpr int OFF_PTO = 70660;  // 1682*28
constexpr int OFF_NU  = 117756; // 943*256
constexpr int OFF_NT  = 359164; // 1682*256
constexpr size_t OFF_UT = 789756; // 943*1682
constexpr size_t TOT_FLOATS = OFF_UT + (size_t)943 * 1682;
constexpr size_t TOT_BYTES  = TOT_FLOATS * 4;

__device__ inline float dot64(const float* __restrict__ a, const float* __restrict__ b) {
    float s = 0.f;
    #pragma unroll
    for (int k = 0; k < 64; k += 4) {
        const float4 av = *reinterpret_cast<const float4*>(a + k);
        const float4 bv = *reinterpret_cast<const float4*>(b + k);
        s += av.x * bv.x + av.y * bv.y + av.z * bv.z + av.w * bv.w;
    }
    return s;
}

// ---- K1: setup, flat job index over 32 blocks ----
// jobs: [0,4096) chunk basis (e,k4) ; [..+89) tiny dots/consts ;
//       [..+1248) BU/BT/ASM float4 copies ; [..+2625) user_w/item_w copies
constexpr int K1_JOBS   = 4096 + 89 + 1248 + 2625; // 8058
constexpr int K1_BLOCKS = (K1_JOBS + 255) / 256;   // 32

__global__ __launch_bounds__(256) void k1_setup(
    const float* __restrict__ AU, const float* __restrict__ AI,
    const float* __restrict__ GU, const float* __restrict__ GI,
    const float* __restrict__ OU, const float* __restrict__ OI,
    const float* __restrict__ MU, const float* __restrict__ MI,
    const float* __restrict__ user_w, const float* __restrict__ item_w,
    const float* __restrict__ lin_w, const float* __restrict__ lin_b,
    float* __restrict__ ws)
{
    int gid = blockIdx.x * 256 + threadIdx.x;

    if (gid < 4096) {                       // chunk-basis: e = gid>>4, k4 = gid&15
        const int e = gid >> 4, k4 = gid & 15;
        int j0, L, s;
        if (e < 128)      { j0 = 0;  L = 7; s = e; }
        else if (e < 192) { j0 = 7;  L = 6; s = e - 128; }
        else              { j0 = 13; L = 6; s = e - 192; }
        float4 su = make_float4(0.f, 0.f, 0.f, 0.f);
        float4 si = make_float4(0.f, 0.f, 0.f, 0.f);
        for (int b = 0; b < L; ++b) if ((s >> b) & 1) {
            const float4 mu = *reinterpret_cast<const float4*>(MU + (j0 + b) * 64 + k4 * 4);
            const float4 mi = *reinterpret_cast<const float4*>(MI + (j0 + b) * 64 + k4 * 4);
            su.x += mu.x; su.y += mu.y; su.z += mu.z; su.w += mu.w;
            si.x += mi.x; si.y += mi.y; si.z += mi.z; si.w += mi.w;
        }
        *reinterpret_cast<float4*>(ws + OFF_CMU + e * 64 + k4 * 4) = su;
        *reinterpret_cast<float4*>(ws + OFF_CMI + e * 64 + k4 * 4) = si;
        if (k4 == 0) {
            float lc = 0.f;
            for (int b = 0; b < L; ++b) if ((s >> b) & 1) lc += lin_w[24 + j0 + b];
            ws[OFF_LWC + e] = lc;
        }
        return;
    }
    gid -= 4096;

    if (gid < 89) {                         // tiny dots + consts
        float S = 0.f;
        for (int k = 0; k < 43; ++k) S += lin_w[k];
        const int i = gid;
        if (i == 0)       { ws[0] = S; ws[1] = lin_b[0]; ws[2] = lin_w[0]; }
        else if (i < 3)   { ws[OFF_LWG + i - 1] = lin_w[i]; }
        else if (i < 24)  { ws[OFF_LWO + i - 3] = lin_w[i]; }
        else if (i < 26)  { int g = i - 24; ws[OFF_AG + g] = S * dot64(AU, GU + g * 64); }
        else if (i < 47)  { int o = i - 26; ws[OFF_AO + o] = S * dot64(AU, OU + o * 64); }
        else              { int j = i - 47; ws[OFF_GO + j] = S * dot64(GU + (j / 21) * 64, OU + (j % 21) * 64); }
        return;
    }
    gid -= 89;

    if (gid < 1248) {                       // float4 copies: BU(432) BT(432) ASM(384)
        int idx = gid, dst; const int c4 = (gid & 15) * 4;
        float4 v = make_float4(0.f, 0.f, 0.f, 0.f);
        if (idx < 432) {
            const int r = idx >> 4; dst = OFF_BU + r * 64 + c4;
            if (r < 21)       v = *reinterpret_cast<const float4*>(OU + r * 64 + c4);
            else if (r == 24) v = *reinterpret_cast<const float4*>(AU + c4);
            else if (r >= 25) v = *reinterpret_cast<const float4*>(GU + (r - 25) * 64 + c4);
        } else if ((idx -= 432) < 432) {
            const int r = idx >> 4; dst = OFF_BT + r * 64 + c4;
            if (r < 21)       v = *reinterpret_cast<const float4*>(OI + r * 64 + c4);
            else if (r == 24) v = *reinterpret_cast<const float4*>(AI + c4);
            else if (r >= 25) v = *reinterpret_cast<const float4*>(GI + (r - 25) * 64 + c4);
        } else {
            idx -= 432;
            const int r = idx >> 4; dst = OFF_ASM + r * 64 + c4;
            if (r < 21)       v = *reinterpret_cast<const float4*>(OI + r * 64 + c4);
            else if (r < 23)  v = *reinterpret_cast<const float4*>(GI + (r - 21) * 64 + c4);
            else              v = *reinterpret_cast<const float4*>(AI + c4);
        }
        *reinterpret_cast<float4*>(ws + dst) = v;
        return;
    }
    gid -= 1248;

    if (gid < 943)  { ws[OFF_PUO + gid * 28 + 27] = user_w[gid]; return; }
    gid -= 943;
    if (gid < 1682) { ws[OFF_PTO + gid * 28 + 27] = item_w[gid]; return; }
}

// ---- K2: generic tiled GEMM  C[r][c] = S * dot(A[r], B[c]) (+lwchunk) ----
constexpr int K2_BLOCKS = 405 + 60 + 108 + 15 + 27 + 4;

__global__ __launch_bounds__(256) void k2_gemm(
    const float* __restrict__ UI, const float* __restrict__ TI,
    const float* __restrict__ UU, const float* __restrict__ TU,
    float* __restrict__ ws)
{
    __shared__ __align__(16) float As[64][68];
    __shared__ __align__(16) float Bs[64][68];

    int b = blockIdx.x;
    const float* Ap; const float* Bp; float* Cp;
    int AR, BR, CS, r0, c0; bool alw = false;
    if (b < 405)              { Ap = UI; AR = 943;  Bp = TU;           BR = 1682; Cp = ws + OFF_UT;  CS = 1682; r0 = (b / 27) * 64; c0 = (b % 27) * 64; }
    else if ((b -= 405) < 60) { Ap = UI; AR = 943;  Bp = ws + OFF_CMU; BR = 256;  Cp = ws + OFF_NU;  CS = 256;  r0 = (b / 4) * 64;  c0 = (b % 4) * 64; }
    else if ((b -= 60) < 108) { Ap = TI; AR = 1682; Bp = ws + OFF_CMI; BR = 256;  Cp = ws + OFF_NT;  CS = 256;  r0 = (b / 4) * 64;  c0 = (b % 4) * 64; }
    else if ((b -= 108) < 15) { Ap = UU; AR = 943;  Bp = ws + OFF_BU;  BR = 27;   Cp = ws + OFF_PUO; CS = 28;   r0 = b * 64;        c0 = 0; }
    else if ((b -= 15) < 27)  { Ap = TU; AR = 1682; Bp = ws + OFF_BT;  BR = 27;   Cp = ws + OFF_PTO; CS = 28;   r0 = b * 64;        c0 = 0; }
    else { b -= 27;             Ap = ws + OFF_ASM; AR = 24; Bp = ws + OFF_CMU; BR = 256; Cp = ws + OFF_NO; CS = 256; r0 = 0; c0 = b * 64; alw = true; }

    const float S = ws[0];
    const int tid = threadIdx.x;

    #pragma unroll
    for (int i = 0; i < 4; ++i) {
        const int q  = tid + i * 256;
        const int r  = q >> 4;
        const int c4 = (q & 15) * 4;
        float4 va = make_float4(0.f, 0.f, 0.f, 0.f);
        if (r0 + r < AR) va = *reinterpret_cast<const float4*>(Ap + (size_t)(r0 + r) * 64 + c4);
        As[c4 + 0][r] = va.x; As[c4 + 1][r] = va.y; As[c4 + 2][r] = va.z; As[c4 + 3][r] = va.w;
        float4 vb = make_float4(0.f, 0.f, 0.f, 0.f);
        if (c0 + r < BR) vb = *reinterpret_cast<const float4*>(Bp + (size_t)(c0 + r) * 64 + c4);
        Bs[c4 + 0][r] = vb.x; Bs[c4 + 1][r] = vb.y; Bs[c4 + 2][r] = vb.z; Bs[c4 + 3][r] = vb.w;
    }
    __syncthreads();

    const int tx = tid & 15, ty = tid >> 4;
    float acc[4][4] = {};
    #pragma unroll 8
    for (int k = 0; k < 64; ++k) {
        const float4 a = *reinterpret_cast<const float4*>(&As[k][ty * 4]);
        const float4 bv = *reinterpret_cast<const float4*>(&Bs[k][tx * 4]);
        const float av[4] = {a.x, a.y, a.z, a.w};
        const float bw[4] = {bv.x, bv.y, bv.z, bv.w};
        #pragma unroll
        for (int i = 0; i < 4; ++i)
            #pragma unroll
            for (int j = 0; j < 4; ++j)
                acc[i][j] += av[i] * bw[j];
    }

    #pragma unroll
    for (int i = 0; i < 4; ++i) {
        const int gr = r0 + ty * 4 + i;
        if (gr >= AR) continue;
        #pragma unroll
        for (int j = 0; j < 4; ++j) {
            const int gc = c0 + tx * 4 + j;
            if (gc >= BR) continue;
            float v = S * acc[i][j];
            if (alw && (gr == 21 || gr == 22)) v += ws[OFF_LWC + gc];
            Cp[(size_t)gr * CS + gc] = v;
        }
    }
}

// ---- F: main thread-per-row kernel ----
__global__ __launch_bounds__(256) void ffm_main(const float* __restrict__ fv,
                                                const float* __restrict__ ws,
                                                float* __restrict__ out) {
    __shared__ float T[864];
    __shared__ __align__(16) float SF[4][64 * NFEAT];
    const int tid  = threadIdx.x;
    const int lane = tid & 63;
    const int wid  = tid >> 6;
    for (int i = tid; i < 96;  i += 256) T[i]       = ws[i];
    for (int i = tid; i < 512; i += 256) T[96 + i]  = ws[OFF_NF + i];
    for (int i = tid; i < 256; i += 256) T[608 + i] = ws[OFF_NA + i];

    const int row0 = blockIdx.x * 256;
    {
        const float* src = fv + (size_t)(row0 + wid * 64) * NFEAT;
        float* sf = SF[wid];
        #pragma unroll
        for (int i = 0; i < 11; ++i) {
            const int s4 = i * 64 + lane;
            *reinterpret_cast<float4*>(sf + s4 * 4) =
                *reinterpret_cast<const float4*>(src + s4 * 4);
        }
        sf[2816 + lane] = src[2816 + lane];
    }
    __syncthreads();

    const float* f = SF[wid] + lane * NFEAT;
    const int   uid = (int)f[0];
    const int   iid = (int)f[1];
    const float age = f[2];
    const int   g   = (f[4] > 0.5f) ? 1 : 0;
    float oacc = 0.f, macc = 0.f;
    #pragma unroll
    for (int k = 1; k < 21; ++k) oacc += f[5 + k] * (float)k;
    const int o = (int)oacc;
    #pragma unroll
    for (int j = 0; j < 19; ++j) macc += f[26 + j] * (float)(1u << j);
    const unsigned m  = (unsigned)macc;
    const unsigned c0 = m & 127u, c1 = (m >> 7) & 63u, c2 = m >> 13;

    const float* pu = ws + OFF_PUO + uid * 28;
    const float* pt = ws + OFF_PTO + iid * 28;
    const float4 puq = *reinterpret_cast<const float4*>(pu + 24);
    const float4 ptq = *reinterpret_cast<const float4*>(pt + 24);
    const float ouv = pu[o];
    const float otv = pt[o];
    const float utv = ws[OFF_UT + (size_t)uid * 1682 + iid];
    const float* nu = ws + OFF_NU + uid * 256;
    const float nuv = nu[c0] + nu[128 + c1] + nu[192 + c2];
    const float* nt = ws + OFF_NT + iid * 256;
    const float ntv = nt[c0] + nt[128 + c1] + nt[192 + c2];
    const float* no = ws + OFF_NO + o * 256;
    const float nov = no[c0] + no[128 + c1] + no[192 + c2];
    const float* nf = T + 96 + g * 256;
    const float nfv = nf[c0] + nf[128 + c1] + nf[192 + c2];
    const float* na = T + 608;
    const float nav = na[c0] + na[128 + c1] + na[192 + c2];

    const float total =
          puq.w + ptq.w + T[1]
        + age * T[2] + T[OFF_LWG + g] + T[OFF_LWO + o]
        + age * (T[OFF_AG + g] + T[OFF_AO + o] + puq.x + ptq.x)
        + (g ? puq.z : puq.y) + (g ? ptq.z : ptq.y)
        + T[OFF_GO + g * 21 + o] + ouv + otv + utv
        + nfv + age * nav + nov + nuv + ntv;

    out[row0 + wid * 64 + lane] = 1.f / (1.f + __expf(-total));
}

// ---- fallback (round-2 kernel) if ws is too small ----
constexpr int RPW = 16, THREADS = 256, WPB = 4, FPW = RPW * NFEAT;
__global__ __launch_bounds__(THREADS) void ffm_fallback(
    const float* __restrict__ fv,
    const float* __restrict__ AU, const float* __restrict__ AI,
    const float* __restrict__ GU, const float* __restrict__ GI,
    const float* __restrict__ OU, const float* __restrict__ OI,
    const float* __restrict__ MU, const float* __restrict__ MI,
    const float* __restrict__ UU, const float* __restrict__ UI,
    const float* __restrict__ TU, const float* __restrict__ TI,
    const float* __restrict__ user_w, const float* __restrict__ item_w,
    const float* __restrict__ lin_w, const float* __restrict__ lin_b,
    float* __restrict__ out)
{
    __shared__ __align__(16) float stage[WPB][FPW];
    const int lane = threadIdx.x & 63;
    const int wid  = threadIdx.x >> 6;
    const int rowBase = (blockIdx.x * WPB + wid) * RPW;
    {
        const float* src = fv + (size_t)rowBase * NFEAT;
        float* dst = stage[wid];
        #pragma unroll
        for (int t = 0; t < 3; ++t) {
            const int idx = t * 64 + lane;
            if (idx < FPW / 4)
                *reinterpret_cast<float4*>(dst + idx * 4) =
                    *reinterpret_cast<const float4*>(src + idx * 4);
        }
    }
    const float* Srow = stage[wid];
    const float au_w = AU[lane], ai_w = AI[lane];
    const float gu0 = GU[lane], gu1 = GU[64 + lane];
    const float gi0 = GI[lane], gi1 = GI[64 + lane];
    const float lw = (lane >= 2 && lane < NFEAT) ? lin_w[lane - 2] : 0.0f;
    const float bias = lin_b[0];
    float sum_lin = lw;
    #pragma unroll
    for (int off = 32; off; off >>= 1) sum_lin += __shfl_xor(sum_lin, off);
    float myval = 0.0f;
    for (int r = 0; r < RPW; ++r) {
        const float* rp = Srow + r * NFEAT;
        const float x = (lane < NFEAT) ? rp[lane] : 0.0f;
        const int uid = (int)rp[0], iid = (int)rp[1];
        const float age = rp[2], g0 = rp[3], g1 = rp[4];
        const unsigned long long ball = __ballot(x != 0.0f);
        const unsigned occm = (unsigned)((ball >> 5) & 0x1FFFFFull);
        unsigned movm = (unsigned)((ball >> 26) & 0x7FFFFull);
        const float au = age * au_w, ai = age * ai_w;
        const float gu = g0 * gu0 + g1 * gu1, gi = g0 * gi0 + g1 * gi1;
        float ou = 0.0f, oi = 0.0f;
        if (occm) { const int j = __builtin_ctz(occm); ou = OU[j * 64 + lane]; oi = OI[j * 64 + lane]; }
        float mu = 0.0f, mi = 0.0f;
        while (movm) { const int j = __builtin_ctz(movm); movm &= movm - 1; mu += MU[j * 64 + lane]; mi += MI[j * 64 + lane]; }
        const float uu = UU[uid * 64 + lane], ui_ = UI[uid * 64 + lane];
        const float tu = TU[iid * 64 + lane], ti = TI[iid * 64 + lane];
        const float part = (ai + gi + oi) * (mu + tu) + au * (gu + ou + uu)
                         + gu * (ou + uu) + ou * uu + mu * ui_ + mi * ti + ui_ * tu;
        float red = part * sum_lin + x * lw;
        #pragma unroll
        for (int off = 32; off; off >>= 1) red += __shfl_xor(red, off);
        const float val = user_w[uid] + item_w[iid] + bias + red;
        if (lane == r) myval = val;
    }
    if (lane < RPW) out[rowBase + lane] = 1.0f / (1.0f + __expf(-myval));
}

extern "C" void kernel_launch(void* const* d_in, const int* in_sizes, int n_in,
                              void* d_out, int out_size, void* d_ws, size_t ws_size,
                              hipStream_t stream) {
    const float* fv = (const float*)d_in[0];
    const float* AU = (const float*)d_in[1];
    const float* AI = (const float*)d_in[2];
    const float* GU = (const float*)d_in[3];
    const float* GI = (const float*)d_in[4];
    const float* OU = (const float*)d_in[5];
    const float* OI = (const float*)d_in[6];
    const float* MU = (const float*)d_in[7];
    const float* MI = (const float*)d_in[8];
    const float* UU = (const float*)d_in[9];
    const float* UI = (const float*)d_in[10];
    const float* TU = (const float*)d_in[11];
    const float* TI = (const float*)d_in[12];
    const float* uw = (const float*)d_in[13];
    const float* iw = (const float*)d_in[14];
    const float* lw = (const float*)d_in[15];
    const float* lb = (const float*)d_in[16];
    float* out = (float*)d_out;
    float* ws  = (float*)d_ws;

    if (ws_size < TOT_BYTES) {
        ffm_fallback<<<B_ROWS / RPW / WPB, THREADS, 0, stream>>>(
            fv, AU, AI, GU, GI, OU, OI, MU, MI, UU, UI, TU, TI, uw, iw, lw, lb, out);
        return;
    }

    k1_setup<<<K1_BLOCKS, 256, 0, stream>>>(AU, AI, GU, GI, OU, OI, MU, MI, uw, iw, lw, lb, ws);
    k2_gemm<<<K2_BLOCKS, 256, 0, stream>>>(UI, TI, UU, TU, ws);
    ffm_main<<<B_ROWS / 256, 256, 0, stream>>>(fv, ws, out);
}

// Round 6
// 44.569 us; speedup vs baseline: 2.4894x; 1.1113x over previous
//
#include <hip/hip_runtime.h>
#include <math.h>

// FFM_69664369541798 — round 6: three-dispatch pipeline.
// KA: [compress fv->12B codes (1024 blk)] + [UT bf16 GEMM (405 blk)] + [k1 jobs (32 blk)]
// KB: small GEMMs (NU/NT bf16, PUO/PTO, NO/NF/NA)  (214 blk)
// F : pure-gather scoring, 25KB LDS, high occupancy (1024 blk)

constexpr int B_ROWS = 262144;
constexpr int NFEAT  = 45;

// ---- ws layout (float-element offsets) ----
constexpr int OFF_LWG = 8;        // 2
constexpr int OFF_LWO = 10;       // 21
constexpr int OFF_AG  = 31;       // 2
constexpr int OFF_AO  = 33;       // 21
constexpr int OFF_GO  = 54;       // 42 -> 96
constexpr int OFF_LWC = 96;       // 256
constexpr int OFF_CMU = 352;      // 256*64
constexpr int OFF_CMI = 16736;    // 256*64
constexpr int OFF_BU  = 33120;    // 27*64
constexpr int OFF_BT  = 34848;    // 27*64
constexpr int OFF_ASM = 36576;    // 24*64
constexpr int OFF_NO  = 38112;    // 21*256
constexpr int OFF_NF  = 43488;    // 2*256
constexpr int OFF_NA  = 44000;    // 256
constexpr int OFF_PUO = 44256;    // 943*28
constexpr int OFF_PTO = 70660;    // 1682*28
constexpr int OFF_NUB = 117756;   // bf16 943*256  (120704 float slots)
constexpr int OFF_NTB = 238460;   // bf16 1682*256 (215296 float slots)
constexpr int OFF_UTB = 453756;   // bf16 943*1682 (793064 float slots)
constexpr int OFF_AGE = 1246820;  // 262144 f32
constexpr int OFF_CA  = 1508964;  // 262144 u32
constexpr int OFF_CM  = 1771108;  // 262144 u32
constexpr size_t TOT_FLOATS = 2033252;
constexpr size_t TOT_BYTES  = TOT_FLOATS * 4;

__device__ inline float dot64(const float* __restrict__ a, const float* __restrict__ b) {
    float s = 0.f;
    #pragma unroll
    for (int k = 0; k < 64; k += 4) {
        const float4 av = *reinterpret_cast<const float4*>(a + k);
        const float4 bv = *reinterpret_cast<const float4*>(b + k);
        s += av.x * bv.x + av.y * bv.y + av.z * bv.z + av.w * bv.w;
    }
    return s;
}
__device__ inline unsigned short f2b(float x) {            // f32 -> bf16 RNE
    union { float f; unsigned u; } v; v.f = x;
    return (unsigned short)((v.u + 0x7FFFu + ((v.u >> 16) & 1u)) >> 16);
}
__device__ inline float b2f(unsigned short u) {
    union { unsigned u; float f; } v; v.u = (unsigned)u << 16; return v.f;
}

// ================= KA =================
constexpr int KA_COMPRESS = 1024;
constexpr int KA_UT       = 405;
constexpr int K1_JOBS     = 4096 + 89 + 1248 + 2625;       // 8058
constexpr int KA_K1       = (K1_JOBS + 255) / 256;         // 32
constexpr int KA_BLOCKS   = KA_COMPRESS + KA_UT + KA_K1;   // 1461

__global__ __launch_bounds__(256) void ka_kernel(
    const float* __restrict__ fv,
    const float* __restrict__ AU, const float* __restrict__ AI,
    const float* __restrict__ GU, const float* __restrict__ GI,
    const float* __restrict__ OU, const float* __restrict__ OI,
    const float* __restrict__ MU, const float* __restrict__ MI,
    const float* __restrict__ user_w, const float* __restrict__ item_w,
    const float* __restrict__ lin_w, const float* __restrict__ lin_b,
    const float* __restrict__ UI, const float* __restrict__ TU,
    float* __restrict__ ws)
{
    __shared__ __align__(16) float shbuf[11520];   // 46 KB union
    const int tid = threadIdx.x;
    int b = blockIdx.x;

    if (b < KA_COMPRESS) {
        // ---- compress 256 rows -> (age, codeA, codeM) ----
        const int lane = tid & 63, wid = tid >> 6;
        float* sf = shbuf + wid * 2880;
        const float* src = fv + (size_t)(b * 256 + wid * 64) * NFEAT;
        #pragma unroll
        for (int i = 0; i < 11; ++i) {
            const int s4 = i * 64 + lane;
            *reinterpret_cast<float4*>(sf + s4 * 4) =
                *reinterpret_cast<const float4*>(src + s4 * 4);
        }
        sf[2816 + lane] = src[2816 + lane];        // wave-local: no barrier needed
        const float* f = sf + lane * NFEAT;
        const int   uid = (int)f[0];
        const int   iid = (int)f[1];
        const float age = f[2];
        const int   g   = (f[4] > 0.5f) ? 1 : 0;
        float oacc = 0.f, macc = 0.f;
        #pragma unroll
        for (int k = 1; k < 21; ++k) oacc += f[5 + k] * (float)k;
        #pragma unroll
        for (int j = 0; j < 19; ++j) macc += f[26 + j] * (float)(1u << j);
        const int      o = (int)oacc;
        const unsigned m = (unsigned)macc;
        const unsigned ca = (unsigned)uid | ((unsigned)iid << 10) |
                            ((unsigned)o << 21) | ((unsigned)g << 26);
        const unsigned cm = (m & 127u) | (((m >> 7) & 63u) << 8) | ((m >> 13) << 16);
        const int row = b * 256 + wid * 64 + lane;
        ws[OFF_AGE + row] = age;
        reinterpret_cast<unsigned*>(ws + OFF_CA)[row] = ca;
        reinterpret_cast<unsigned*>(ws + OFF_CM)[row] = cm;
        return;
    }
    b -= KA_COMPRESS;

    if (b < KA_UT) {
        // ---- UT tile: UTb[u][t] = bf16( S * dot(UI[u], TU[t]) ) ----
        float S = 0.f;
        for (int k = 0; k < 43; ++k) S += lin_w[k];
        float* As = shbuf;                 // [64][68] k-major
        float* Bs = shbuf + 4352;
        const int r0 = (b / 27) * 64, c0 = (b % 27) * 64;
        #pragma unroll
        for (int i = 0; i < 4; ++i) {
            const int q  = tid + i * 256;
            const int r  = q >> 4;
            const int c4 = (q & 15) * 4;
            float4 va = make_float4(0.f, 0.f, 0.f, 0.f);
            if (r0 + r < 943)  va = *reinterpret_cast<const float4*>(UI + (size_t)(r0 + r) * 64 + c4);
            As[(c4 + 0) * 68 + r] = va.x; As[(c4 + 1) * 68 + r] = va.y;
            As[(c4 + 2) * 68 + r] = va.z; As[(c4 + 3) * 68 + r] = va.w;
            float4 vb = make_float4(0.f, 0.f, 0.f, 0.f);
            if (c0 + r < 1682) vb = *reinterpret_cast<const float4*>(TU + (size_t)(c0 + r) * 64 + c4);
            Bs[(c4 + 0) * 68 + r] = vb.x; Bs[(c4 + 1) * 68 + r] = vb.y;
            Bs[(c4 + 2) * 68 + r] = vb.z; Bs[(c4 + 3) * 68 + r] = vb.w;
        }
        __syncthreads();
        const int tx = tid & 15, ty = tid >> 4;
        float acc[4][4] = {};
        #pragma unroll 8
        for (int k = 0; k < 64; ++k) {
            const float4 a  = *reinterpret_cast<const float4*>(As + k * 68 + ty * 4);
            const float4 bv = *reinterpret_cast<const float4*>(Bs + k * 68 + tx * 4);
            const float av[4] = {a.x, a.y, a.z, a.w};
            const float bw[4] = {bv.x, bv.y, bv.z, bv.w};
            #pragma unroll
            for (int i = 0; i < 4; ++i)
                #pragma unroll
                for (int j = 0; j < 4; ++j)
                    acc[i][j] += av[i] * bw[j];
        }
        unsigned short* UTb = reinterpret_cast<unsigned short*>(ws + OFF_UTB);
        #pragma unroll
        for (int i = 0; i < 4; ++i) {
            const int gr = r0 + ty * 4 + i;
            if (gr >= 943) continue;
            #pragma unroll
            for (int jp = 0; jp < 2; ++jp) {
                const int gc = c0 + tx * 4 + jp * 2;
                if (gc >= 1682) continue;            // gc even -> gc+1 also valid
                ushort2 st;
                st.x = f2b(S * acc[i][jp * 2]);
                st.y = f2b(S * acc[i][jp * 2 + 1]);
                *reinterpret_cast<ushort2*>(UTb + (size_t)gr * 1682 + gc) = st;
            }
        }
        return;
    }
    b -= KA_UT;

    // ---- k1 jobs ----
    int gid = b * 256 + tid;
    if (gid < 4096) {
        const int e = gid >> 4, k4 = gid & 15;
        int j0, L, s;
        if (e < 128)      { j0 = 0;  L = 7; s = e; }
        else if (e < 192) { j0 = 7;  L = 6; s = e - 128; }
        else              { j0 = 13; L = 6; s = e - 192; }
        float4 su = make_float4(0.f, 0.f, 0.f, 0.f);
        float4 si = make_float4(0.f, 0.f, 0.f, 0.f);
        for (int bb = 0; bb < L; ++bb) if ((s >> bb) & 1) {
            const float4 mu = *reinterpret_cast<const float4*>(MU + (j0 + bb) * 64 + k4 * 4);
            const float4 mi = *reinterpret_cast<const float4*>(MI + (j0 + bb) * 64 + k4 * 4);
            su.x += mu.x; su.y += mu.y; su.z += mu.z; su.w += mu.w;
            si.x += mi.x; si.y += mi.y; si.z += mi.z; si.w += mi.w;
        }
        *reinterpret_cast<float4*>(ws + OFF_CMU + e * 64 + k4 * 4) = su;
        *reinterpret_cast<float4*>(ws + OFF_CMI + e * 64 + k4 * 4) = si;
        if (k4 == 0) {
            float lc = 0.f;
            for (int bb = 0; bb < L; ++bb) if ((s >> bb) & 1) lc += lin_w[24 + j0 + bb];
            ws[OFF_LWC + e] = lc;
        }
        return;
    }
    gid -= 4096;
    if (gid < 89) {
        float S = 0.f;
        for (int k = 0; k < 43; ++k) S += lin_w[k];
        const int i = gid;
        if (i == 0)       { ws[0] = S; ws[1] = lin_b[0]; ws[2] = lin_w[0]; }
        else if (i < 3)   { ws[OFF_LWG + i - 1] = lin_w[i]; }
        else if (i < 24)  { ws[OFF_LWO + i - 3] = lin_w[i]; }
        else if (i < 26)  { int g = i - 24; ws[OFF_AG + g] = S * dot64(AU, GU + g * 64); }
        else if (i < 47)  { int o = i - 26; ws[OFF_AO + o] = S * dot64(AU, OU + o * 64); }
        else              { int j = i - 47; ws[OFF_GO + j] = S * dot64(GU + (j / 21) * 64, OU + (j % 21) * 64); }
        return;
    }
    gid -= 89;
    if (gid < 1248) {
        int idx = gid, dst; const int c4 = (gid & 15) * 4;
        float4 v = make_float4(0.f, 0.f, 0.f, 0.f);
        if (idx < 432) {
            const int r = idx >> 4; dst = OFF_BU + r * 64 + c4;
            if (r < 21)       v = *reinterpret_cast<const float4*>(OU + r * 64 + c4);
            else if (r == 24) v = *reinterpret_cast<const float4*>(AU + c4);
            else if (r >= 25) v = *reinterpret_cast<const float4*>(GU + (r - 25) * 64 + c4);
        } else if ((idx -= 432) < 432) {
            const int r = idx >> 4; dst = OFF_BT + r * 64 + c4;
            if (r < 21)       v = *reinterpret_cast<const float4*>(OI + r * 64 + c4);
            else if (r == 24) v = *reinterpret_cast<const float4*>(AI + c4);
            else if (r >= 25) v = *reinterpret_cast<const float4*>(GI + (r - 25) * 64 + c4);
        } else {
            idx -= 432;
            const int r = idx >> 4; dst = OFF_ASM + r * 64 + c4;
            if (r < 21)       v = *reinterpret_cast<const float4*>(OI + r * 64 + c4);
            else if (r < 23)  v = *reinterpret_cast<const float4*>(GI + (r - 21) * 64 + c4);
            else              v = *reinterpret_cast<const float4*>(AI + c4);
        }
        *reinterpret_cast<float4*>(ws + dst) = v;
        return;
    }
    gid -= 1248;
    if (gid < 943)  { ws[OFF_PUO + gid * 28 + 27] = user_w[gid]; return; }
    gid -= 943;
    if (gid < 1682) { ws[OFF_PTO + gid * 28 + 27] = item_w[gid]; return; }
}

// ================= KB: small GEMMs =================
constexpr int KB_BLOCKS = 60 + 108 + 15 + 27 + 4;   // 214

__global__ __launch_bounds__(256) void kb_gemm(
    const float* __restrict__ UI, const float* __restrict__ TI,
    const float* __restrict__ UU, const float* __restrict__ TU,
    float* __restrict__ ws)
{
    __shared__ __align__(16) float As[64 * 68];
    __shared__ __align__(16) float Bs[64 * 68];

    int b = blockIdx.x;
    const float* Ap; const float* Bp;
    int AR, BR, r0, c0, mode;   // 0:NU bf16  1:NT bf16  2:PUO  3:PTO  4:NO/NF/NA
    if (b < 60)             { Ap = UI; AR = 943;  Bp = ws + OFF_CMU; BR = 256; r0 = (b / 4) * 64; c0 = (b % 4) * 64; mode = 0; }
    else if ((b -= 60) < 108){ Ap = TI; AR = 1682; Bp = ws + OFF_CMI; BR = 256; r0 = (b / 4) * 64; c0 = (b % 4) * 64; mode = 1; }
    else if ((b -= 108) < 15){ Ap = UU; AR = 943;  Bp = ws + OFF_BU;  BR = 27;  r0 = b * 64; c0 = 0; mode = 2; }
    else if ((b -= 15) < 27) { Ap = TU; AR = 1682; Bp = ws + OFF_BT;  BR = 27;  r0 = b * 64; c0 = 0; mode = 3; }
    else { b -= 27;            Ap = ws + OFF_ASM; AR = 24; Bp = ws + OFF_CMU; BR = 256; r0 = 0; c0 = b * 64; mode = 4; }

    const float S = ws[0];
    const int tid = threadIdx.x;
    #pragma unroll
    for (int i = 0; i < 4; ++i) {
        const int q  = tid + i * 256;
        const int r  = q >> 4;
        const int c4 = (q & 15) * 4;
        float4 va = make_float4(0.f, 0.f, 0.f, 0.f);
        if (r0 + r < AR) va = *reinterpret_cast<const float4*>(Ap + (size_t)(r0 + r) * 64 + c4);
        As[(c4 + 0) * 68 + r] = va.x; As[(c4 + 1) * 68 + r] = va.y;
        As[(c4 + 2) * 68 + r] = va.z; As[(c4 + 3) * 68 + r] = va.w;
        float4 vb = make_float4(0.f, 0.f, 0.f, 0.f);
        if (c0 + r < BR) vb = *reinterpret_cast<const float4*>(Bp + (size_t)(c0 + r) * 64 + c4);
        Bs[(c4 + 0) * 68 + r] = vb.x; Bs[(c4 + 1) * 68 + r] = vb.y;
        Bs[(c4 + 2) * 68 + r] = vb.z; Bs[(c4 + 3) * 68 + r] = vb.w;
    }
    __syncthreads();

    const int tx = tid & 15, ty = tid >> 4;
    float acc[4][4] = {};
    #pragma unroll 8
    for (int k = 0; k < 64; ++k) {
        const float4 a  = *reinterpret_cast<const float4*>(As + k * 68 + ty * 4);
        const float4 bv = *reinterpret_cast<const float4*>(Bs + k * 68 + tx * 4);
        const float av[4] = {a.x, a.y, a.z, a.w};
        const float bw[4] = {bv.x, bv.y, bv.z, bv.w};
        #pragma unroll
        for (int i = 0; i < 4; ++i)
            #pragma unroll
            for (int j = 0; j < 4; ++j)
                acc[i][j] += av[i] * bw[j];
    }

    if (mode <= 1) {
        unsigned short* Cb = reinterpret_cast<unsigned short*>(ws + (mode == 0 ? OFF_NUB : OFF_NTB));
        #pragma unroll
        for (int i = 0; i < 4; ++i) {
            const int gr = r0 + ty * 4 + i;
            if (gr >= AR) continue;
            #pragma unroll
            for (int jp = 0; jp < 2; ++jp) {
                const int gc = c0 + tx * 4 + jp * 2;   // < 256 always
                ushort2 st;
                st.x = f2b(S * acc[i][jp * 2]);
                st.y = f2b(S * acc[i][jp * 2 + 1]);
                *reinterpret_cast<ushort2*>(Cb + (size_t)gr * 256 + gc) = st;
            }
        }
    } else {
        float* Cp = ws + (mode == 2 ? OFF_PUO : (mode == 3 ? OFF_PTO : OFF_NO));
        const int CS = (mode == 4) ? 256 : 28;
        #pragma unroll
        for (int i = 0; i < 4; ++i) {
            const int gr = r0 + ty * 4 + i;
            if (gr >= AR) continue;
            #pragma unroll
            for (int j = 0; j < 4; ++j) {
                const int gc = c0 + tx * 4 + j;
                if (gc >= BR) continue;
                float v = S * acc[i][j];
                if (mode == 4 && (gr == 21 || gr == 22)) v += ws[OFF_LWC + gc];
                Cp[(size_t)gr * CS + gc] = v;
            }
        }
    }
}

// ================= F: pure-gather scoring =================
__global__ __launch_bounds__(256) void ffm_final(const float* __restrict__ ws,
                                                 float* __restrict__ out)
{
    __shared__ float T[6240];    // consts96 | NF512 | NA256 | NO5376  (25 KB)
    const int tid = threadIdx.x;
    for (int i = tid; i < 96;   i += 256) T[i]        = ws[i];
    for (int i = tid; i < 512;  i += 256) T[96 + i]   = ws[OFF_NF + i];
    for (int i = tid; i < 256;  i += 256) T[608 + i]  = ws[OFF_NA + i];
    for (int i = tid; i < 5376; i += 256) T[864 + i]  = ws[OFF_NO + i];
    __syncthreads();

    const int row = blockIdx.x * 256 + tid;
    const float    age = ws[OFF_AGE + row];
    const unsigned ca  = reinterpret_cast<const unsigned*>(ws + OFF_CA)[row];
    const unsigned cm  = reinterpret_cast<const unsigned*>(ws + OFF_CM)[row];
    const int uid = ca & 1023, iid = (ca >> 10) & 2047, o = (ca >> 21) & 31, g = (ca >> 26) & 1;
    const int c0 = cm & 127, c1 = (cm >> 8) & 63, c2 = (cm >> 16) & 63;

    const float* pu = ws + OFF_PUO + uid * 28;
    const float* pt = ws + OFF_PTO + iid * 28;
    const float4 puq = *reinterpret_cast<const float4*>(pu + 24);
    const float4 ptq = *reinterpret_cast<const float4*>(pt + 24);
    const float ouv = pu[o];
    const float otv = pt[o];

    const unsigned short* UTb = reinterpret_cast<const unsigned short*>(ws + OFF_UTB);
    const float utv = b2f(UTb[(size_t)uid * 1682 + iid]);
    const unsigned short* nu = reinterpret_cast<const unsigned short*>(ws + OFF_NUB) + uid * 256;
    const float nuv = b2f(nu[c0]) + b2f(nu[128 + c1]) + b2f(nu[192 + c2]);
    const unsigned short* nt = reinterpret_cast<const unsigned short*>(ws + OFF_NTB) + iid * 256;
    const float ntv = b2f(nt[c0]) + b2f(nt[128 + c1]) + b2f(nt[192 + c2]);

    const float* no = T + 864 + o * 256;
    const float nov = no[c0] + no[128 + c1] + no[192 + c2];
    const float* nf = T + 96 + g * 256;
    const float nfv = nf[c0] + nf[128 + c1] + nf[192 + c2];
    const float* na = T + 608;
    const float nav = na[c0] + na[128 + c1] + na[192 + c2];

    const float total =
          puq.w + ptq.w + T[1]
        + age * T[2] + T[OFF_LWG + g] + T[OFF_LWO + o]
        + age * (T[OFF_AG + g] + T[OFF_AO + o] + puq.x + ptq.x)
        + (g ? puq.z : puq.y) + (g ? ptq.z : ptq.y)
        + T[OFF_GO + g * 21 + o] + ouv + otv + utv
        + nfv + age * nav + nov + nuv + ntv;

    out[row] = 1.f / (1.f + __expf(-total));
}

// ---- fallback (round-2 kernel) if ws is too small ----
constexpr int RPW = 16, THREADS = 256, WPB = 4, FPW = RPW * NFEAT;
__global__ __launch_bounds__(THREADS) void ffm_fallback(
    const float* __restrict__ fv,
    const float* __restrict__ AU, const float* __restrict__ AI,
    const float* __restrict__ GU, const float* __restrict__ GI,
    const float* __restrict__ OU, const float* __restrict__ OI,
    const float* __restrict__ MU, const float* __restrict__ MI,
    const float* __restrict__ UU, const float* __restrict__ UI,
    const float* __restrict__ TU, const float* __restrict__ TI,
    const float* __restrict__ user_w, const float* __restrict__ item_w,
    const float* __restrict__ lin_w, const float* __restrict__ lin_b,
    float* __restrict__ out)
{
    __shared__ __align__(16) float stage[WPB][FPW];
    const int lane = threadIdx.x & 63;
    const int wid  = threadIdx.x >> 6;
    const int rowBase = (blockIdx.x * WPB + wid) * RPW;
    {
        const float* src = fv + (size_t)rowBase * NFEAT;
        float* dst = stage[wid];
        #pragma unroll
        for (int t = 0; t < 3; ++t) {
            const int idx = t * 64 + lane;
            if (idx < FPW / 4)
                *reinterpret_cast<float4*>(dst + idx * 4) =
                    *reinterpret_cast<const float4*>(src + idx * 4);
        }
    }
    const float* Srow = stage[wid];
    const float au_w = AU[lane], ai_w = AI[lane];
    const float gu0 = GU[lane], gu1 = GU[64 + lane];
    const float gi0 = GI[lane], gi1 = GI[64 + lane];
    const float lw = (lane >= 2 && lane < NFEAT) ? lin_w[lane - 2] : 0.0f;
    const float bias = lin_b[0];
    float sum_lin = lw;
    #pragma unroll
    for (int off = 32; off; off >>= 1) sum_lin += __shfl_xor(sum_lin, off);
    float myval = 0.0f;
    for (int r = 0; r < RPW; ++r) {
        const float* rp = Srow + r * NFEAT;
        const float x = (lane < NFEAT) ? rp[lane] : 0.0f;
        const int uid = (int)rp[0], iid = (int)rp[1];
        const float age = rp[2], g0 = rp[3], g1 = rp[4];
        const unsigned long long ball = __ballot(x != 0.0f);
        const unsigned occm = (unsigned)((ball >> 5) & 0x1FFFFFull);
        unsigned movm = (unsigned)((ball >> 26) & 0x7FFFFull);
        const float au = age * au_w, ai = age * ai_w;
        const float gu = g0 * gu0 + g1 * gu1, gi = g0 * gi0 + g1 * gi1;
        float ou = 0.0f, oi = 0.0f;
        if (occm) { const int j = __builtin_ctz(occm); ou = OU[j * 64 + lane]; oi = OI[j * 64 + lane]; }
        float mu = 0.0f, mi = 0.0f;
        while (movm) { const int j = __builtin_ctz(movm); movm &= movm - 1; mu += MU[j * 64 + lane]; mi += MI[j * 64 + lane]; }
        const float uu = UU[uid * 64 + lane], ui_ = UI[uid * 64 + lane];
        const float tu = TU[iid * 64 + lane], ti = TI[iid * 64 + lane];
        const float part = (ai + gi + oi) * (mu + tu) + au * (gu + ou + uu)
                         + gu * (ou + uu) + ou * uu + mu * ui_ + mi * ti + ui_ * tu;
        float red = part * sum_lin + x * lw;
        #pragma unroll
        for (int off = 32; off; off >>= 1) red += __shfl_xor(red, off);
        const float val = user_w[uid] + item_w[iid] + bias + red;
        if (lane == r) myval = val;
    }
    if (lane < RPW) out[rowBase + lane] = 1.0f / (1.0f + __expf(-myval));
}

extern "C" void kernel_launch(void* const* d_in, const int* in_sizes, int n_in,
                              void* d_out, int out_size, void* d_ws, size_t ws_size,
                              hipStream_t stream) {
    const float* fv = (const float*)d_in[0];
    const float* AU = (const float*)d_in[1];
    const float* AI = (const float*)d_in[2];
    const float* GU = (const float*)d_in[3];
    const float* GI = (const float*)d_in[4];
    const float* OU = (const float*)d_in[5];
    const float* OI = (const float*)d_in[6];
    const float* MU = (const float*)d_in[7];
    const float* MI = (const float*)d_in[8];
    const float* UU = (const float*)d_in[9];
    const float* UI = (const float*)d_in[10];
    const float* TU = (const float*)d_in[11];
    const float* TI = (const float*)d_in[12];
    const float* uw = (const float*)d_in[13];
    const float* iw = (const float*)d_in[14];
    const float* lw = (const float*)d_in[15];
    const float* lb = (const float*)d_in[16];
    float* out = (float*)d_out;
    float* ws  = (float*)d_ws;

    if (ws_size < TOT_BYTES) {
        ffm_fallback<<<B_ROWS / RPW / WPB, THREADS, 0, stream>>>(
            fv, AU, AI, GU, GI, OU, OI, MU, MI, UU, UI, TU, TI, uw, iw, lw, lb, out);
        return;
    }

    ka_kernel<<<KA_BLOCKS, 256, 0, stream>>>(
        fv, AU, AI, GU, GI, OU, OI, MU, MI, uw, iw, lw, lb, UI, TU, ws);
    kb_gemm<<<KB_BLOCKS, 256, 0, stream>>>(UI, TI, UU, TU, ws);
    ffm_final<<<B_ROWS / 256, 256, 0, stream>>>(ws, out);
}

// Round 7
// 43.678 us; speedup vs baseline: 2.5402x; 1.0204x over previous
//
#include <hip/hip_runtime.h>
#include <math.h>

// FFM_69664369541798 — round 7: minimize cache-line transactions per row.
// KA2 (one dispatch): compress fv->codes (1024 blk) + UT bf16 GEMM (405) +
//                     consts (1) + PUO/PTO/DMU/DMT bf16 GEMMs (84) + NO/NF/NA (4)
// F'  : pure-gather scoring — ~5 cache lines per row.

constexpr int B_ROWS = 262144;
constexpr int NFEAT  = 45;

// ---- ws layout (float-element offsets) ----
constexpr int OFF_LWG  = 8;        // 2
constexpr int OFF_LWO  = 10;       // 21
constexpr int OFF_AG   = 31;       // 2
constexpr int OFF_AO   = 33;       // 21
constexpr int OFF_GO   = 54;       // 42 -> 96
constexpr int OFF_NO   = 96;       // 21*256 f32 -> 5472
constexpr int OFF_NF   = 5472;     // 2*256     -> 5984
constexpr int OFF_NA   = 5984;     // 256       -> 6240
constexpr int LDS_TAB  = 6240;
constexpr int OFF_PUOB = 6240;     // bf16 943*32  (15088 f32)
constexpr int OFF_PTOB = 21328;    // bf16 1682*32 (26912 f32)
constexpr int OFF_DMUB = 48240;    // bf16 943*32  (15088 f32)
constexpr int OFF_DMTB = 63328;    // bf16 1682*32 (26912 f32)
constexpr int OFF_UTB  = 90240;    // bf16 943*1682 (793064 f32)
constexpr int OFF_AGE  = 883304;   // 262144 f32
constexpr int OFF_CA   = 1145448;  // 262144 u32
constexpr int OFF_CM   = 1407592;  // 262144 u32
constexpr size_t TOT_FLOATS = 1669736;
constexpr size_t TOT_BYTES  = TOT_FLOATS * 4;

__device__ inline float dot64(const float* __restrict__ a, const float* __restrict__ b) {
    float s = 0.f;
    #pragma unroll
    for (int k = 0; k < 64; k += 4) {
        const float4 av = *reinterpret_cast<const float4*>(a + k);
        const float4 bv = *reinterpret_cast<const float4*>(b + k);
        s += av.x * bv.x + av.y * bv.y + av.z * bv.z + av.w * bv.w;
    }
    return s;
}
__device__ inline unsigned short f2b(float x) {            // f32 -> bf16 RNE
    union { float f; unsigned u; } v; v.f = x;
    return (unsigned short)((v.u + 0x7FFFu + ((v.u >> 16) & 1u)) >> 16);
}
__device__ inline float b2f(unsigned short u) {
    union { unsigned u; float f; } v; v.u = (unsigned)u << 16; return v.f;
}

// block ranges inside KA2
constexpr int KA_COMPRESS = 1024;
constexpr int KA_UT       = 405;                 // 15 x 27 tiles
constexpr int KA_CONST    = 1;
constexpr int KA_PUO      = 15;
constexpr int KA_PTO      = 27;
constexpr int KA_DMU      = 15;
constexpr int KA_DMT      = 27;
constexpr int KA_NOX      = 4;
constexpr int KA2_BLOCKS  = KA_COMPRESS + KA_UT + KA_CONST + KA_PUO + KA_PTO
                          + KA_DMU + KA_DMT + KA_NOX;   // 1518

__global__ __launch_bounds__(256) void ka2_kernel(
    const float* __restrict__ fv,
    const float* __restrict__ AU, const float* __restrict__ AI,
    const float* __restrict__ GU, const float* __restrict__ GI,
    const float* __restrict__ OU, const float* __restrict__ OI,
    const float* __restrict__ MU, const float* __restrict__ MI,
    const float* __restrict__ UU, const float* __restrict__ UI,
    const float* __restrict__ TU, const float* __restrict__ TI,
    const float* __restrict__ user_w, const float* __restrict__ item_w,
    const float* __restrict__ lin_w, const float* __restrict__ lin_b,
    float* __restrict__ ws)
{
    __shared__ __align__(16) float shbuf[11520];   // compress stage / GEMM tiles
    const int tid = threadIdx.x;
    int b = blockIdx.x;

    if (b < KA_COMPRESS) {
        // ---- compress 256 rows -> (age, codeA, rawMask) ----
        const int lane = tid & 63, wid = tid >> 6;
        float* sf = shbuf + wid * 2880;
        const float* src = fv + (size_t)(b * 256 + wid * 64) * NFEAT;
        #pragma unroll
        for (int i = 0; i < 11; ++i) {
            const int s4 = i * 64 + lane;
            *reinterpret_cast<float4*>(sf + s4 * 4) =
                *reinterpret_cast<const float4*>(src + s4 * 4);
        }
        sf[2816 + lane] = src[2816 + lane];        // wave-local, no barrier
        const float* f = sf + lane * NFEAT;
        const int   uid = (int)f[0];
        const int   iid = (int)f[1];
        const float age = f[2];
        const int   g   = (f[4] > 0.5f) ? 1 : 0;
        float oacc = 0.f, macc = 0.f;
        #pragma unroll
        for (int k = 1; k < 21; ++k) oacc += f[5 + k] * (float)k;
        #pragma unroll
        for (int j = 0; j < 19; ++j) macc += f[26 + j] * (float)(1u << j);
        const int      o = (int)oacc;
        const unsigned m = (unsigned)macc;
        const unsigned ca = (unsigned)uid | ((unsigned)iid << 10) |
                            ((unsigned)o << 21) | ((unsigned)g << 26);
        const int row = b * 256 + wid * 64 + lane;
        ws[OFF_AGE + row] = age;
        reinterpret_cast<unsigned*>(ws + OFF_CA)[row] = ca;
        reinterpret_cast<unsigned*>(ws + OFF_CM)[row] = m;
        return;
    }
    b -= KA_COMPRESS;

    // ---- consts block ----
    if (b == KA_UT) {          // placed between UT and small GEMMs
        float S = 0.f;
        for (int k = 0; k < 43; ++k) S += lin_w[k];
        const int i = tid;
        if (i == 0)       { ws[0] = S; ws[1] = lin_b[0]; ws[2] = lin_w[0]; }
        else if (i < 3)   { ws[OFF_LWG + i - 1] = lin_w[i]; }
        else if (i < 24)  { ws[OFF_LWO + i - 3] = lin_w[i]; }
        else if (i < 26)  { int g = i - 24; ws[OFF_AG + g] = S * dot64(AU, GU + g * 64); }
        else if (i < 47)  { int o = i - 26; ws[OFF_AO + o] = S * dot64(AU, OU + o * 64); }
        else if (i < 89)  { int j = i - 47; ws[OFF_GO + j] = S * dot64(GU + (j / 21) * 64, OU + (j % 21) * 64); }
        return;
    }

    // ---- GEMM modes ----
    // 0: UT   A=UI(943)  B=TU(1682)      -> bf16 UTB   stride 1682
    // 1: PUO  A=UU(943)  B={OU,AU,GU}    -> bf16 PUOB  stride 32 (+user_w col 27)
    // 2: PTO  A=TU(1682) B={OI,AI,GI}    -> bf16 PTOB  stride 32 (+item_w col 27)
    // 3: DMU  A=UI(943)  B=MU(19)        -> bf16 DMUB  stride 32
    // 4: DMT  A=TI(1682) B=MI(19)        -> bf16 DMTB  stride 32
    // 5: NOX  A={OI,GI,AI}(24) B=CMU(256)-> f32  NO/NF/NA stride 256 (+lwchunk rows 21,22)
    int mode, AR, BR, r0 = 0, c0 = 0;
    if (b < KA_UT)              { mode = 0; AR = 943;  BR = 1682; r0 = (b / 27) * 64; c0 = (b % 27) * 64; }
    else if ((b -= KA_UT + 1) < KA_PUO) { mode = 1; AR = 943;  BR = 28;  r0 = b * 64; }
    else if ((b -= KA_PUO) < KA_PTO)    { mode = 2; AR = 1682; BR = 28;  r0 = b * 64; }
    else if ((b -= KA_PTO) < KA_DMU)    { mode = 3; AR = 943;  BR = 19;  r0 = b * 64; }
    else if ((b -= KA_DMU) < KA_DMT)    { mode = 4; AR = 1682; BR = 19;  r0 = b * 64; }
    else { b -= KA_DMT;                   mode = 5; AR = 24;   BR = 256; c0 = b * 64; }

    float S = 0.f;
    for (int k = 0; k < 43; ++k) S += lin_w[k];

    float* As = shbuf;            // [64][68] k-major
    float* Bs = shbuf + 4352;
    #pragma unroll
    for (int i = 0; i < 4; ++i) {
        const int q  = tid + i * 256;
        const int r  = q >> 4;
        const int c4 = (q & 15) * 4;
        // ---- A tile ----
        float4 va = make_float4(0.f, 0.f, 0.f, 0.f);
        if (r0 + r < AR) {
            if (mode == 5) {
                const int rr = r0 + r;
                const float* srcp = (rr < 21) ? OI + rr * 64
                                  : (rr == 21) ? GI : (rr == 22) ? GI + 64 : AI;
                va = *reinterpret_cast<const float4*>(srcp + c4);
            } else {
                const float* Ap = (mode == 0) ? UI : (mode == 1) ? UU
                                : (mode == 2) ? TU : (mode == 3) ? UI : TI;
                va = *reinterpret_cast<const float4*>(Ap + (size_t)(r0 + r) * 64 + c4);
            }
        }
        As[(c4 + 0) * 68 + r] = va.x; As[(c4 + 1) * 68 + r] = va.y;
        As[(c4 + 2) * 68 + r] = va.z; As[(c4 + 3) * 68 + r] = va.w;
        // ---- B tile (col cr = c0 + r) ----
        float4 vb = make_float4(0.f, 0.f, 0.f, 0.f);
        const int cr = c0 + r;
        if (mode == 0) {
            if (cr < 1682) vb = *reinterpret_cast<const float4*>(TU + (size_t)cr * 64 + c4);
        } else if (mode == 1 || mode == 2) {
            const float* srcp = nullptr;
            if (mode == 1) srcp = (r < 21) ? OU + r * 64 : (r == 24) ? AU
                                 : (r == 25) ? GU : (r == 26) ? GU + 64 : nullptr;
            else           srcp = (r < 21) ? OI + r * 64 : (r == 24) ? AI
                                 : (r == 25) ? GI : (r == 26) ? GI + 64 : nullptr;
            if (srcp) vb = *reinterpret_cast<const float4*>(srcp + c4);
        } else if (mode == 3) {
            if (r < 19) vb = *reinterpret_cast<const float4*>(MU + r * 64 + c4);
        } else if (mode == 4) {
            if (r < 19) vb = *reinterpret_cast<const float4*>(MI + r * 64 + c4);
        } else {
            const int e = cr; int j0, L, s;
            if (e < 128)      { j0 = 0;  L = 7; s = e; }
            else if (e < 192) { j0 = 7;  L = 6; s = e - 128; }
            else              { j0 = 13; L = 6; s = e - 192; }
            for (int bb = 0; bb < L; ++bb) if ((s >> bb) & 1) {
                const float4 mu = *reinterpret_cast<const float4*>(MU + (j0 + bb) * 64 + c4);
                vb.x += mu.x; vb.y += mu.y; vb.z += mu.z; vb.w += mu.w;
            }
        }
        Bs[(c4 + 0) * 68 + r] = vb.x; Bs[(c4 + 1) * 68 + r] = vb.y;
        Bs[(c4 + 2) * 68 + r] = vb.z; Bs[(c4 + 3) * 68 + r] = vb.w;
    }
    __syncthreads();

    const int tx = tid & 15, ty = tid >> 4;
    float acc[4][4] = {};
    #pragma unroll 8
    for (int k = 0; k < 64; ++k) {
        const float4 a  = *reinterpret_cast<const float4*>(As + k * 68 + ty * 4);
        const float4 bv = *reinterpret_cast<const float4*>(Bs + k * 68 + tx * 4);
        const float av[4] = {a.x, a.y, a.z, a.w};
        const float bw[4] = {bv.x, bv.y, bv.z, bv.w};
        #pragma unroll
        for (int i = 0; i < 4; ++i)
            #pragma unroll
            for (int j = 0; j < 4; ++j)
                acc[i][j] += av[i] * bw[j];
    }

    if (mode == 0) {
        unsigned short* UTb = reinterpret_cast<unsigned short*>(ws + OFF_UTB);
        #pragma unroll
        for (int i = 0; i < 4; ++i) {
            const int gr = r0 + ty * 4 + i;
            if (gr >= 943) continue;
            #pragma unroll
            for (int jp = 0; jp < 2; ++jp) {
                const int gc = c0 + tx * 4 + jp * 2;
                if (gc >= 1682) continue;
                ushort2 st;
                st.x = f2b(S * acc[i][jp * 2]);
                st.y = f2b(S * acc[i][jp * 2 + 1]);
                *reinterpret_cast<ushort2*>(UTb + (size_t)gr * 1682 + gc) = st;
            }
        }
    } else if (mode == 1 || mode == 2) {
        unsigned short* Cb = reinterpret_cast<unsigned short*>(ws + (mode == 1 ? OFF_PUOB : OFF_PTOB));
        const float* wvec = (mode == 1) ? user_w : item_w;
        #pragma unroll
        for (int i = 0; i < 4; ++i) {
            const int gr = r0 + ty * 4 + i;
            if (gr >= AR) continue;
            #pragma unroll
            for (int j = 0; j < 4; ++j) {
                const int gc = tx * 4 + j;
                if (gc >= 28) continue;
                Cb[(size_t)gr * 32 + gc] = (gc == 27) ? f2b(wvec[gr]) : f2b(S * acc[i][j]);
            }
        }
    } else if (mode == 3 || mode == 4) {
        unsigned short* Cb = reinterpret_cast<unsigned short*>(ws + (mode == 3 ? OFF_DMUB : OFF_DMTB));
        #pragma unroll
        for (int i = 0; i < 4; ++i) {
            const int gr = r0 + ty * 4 + i;
            if (gr >= AR) continue;
            #pragma unroll
            for (int j = 0; j < 4; ++j) {
                const int gc = tx * 4 + j;
                if (gc >= 19) continue;
                Cb[(size_t)gr * 32 + gc] = f2b(S * acc[i][j]);
            }
        }
    } else {
        #pragma unroll
        for (int i = 0; i < 4; ++i) {
            const int gr = ty * 4 + i;
            if (gr >= 24) continue;
            #pragma unroll
            for (int j = 0; j < 4; ++j) {
                const int gc = c0 + tx * 4 + j;
                float v = S * acc[i][j];
                if (gr == 21 || gr == 22) {        // NF rows: + lwchunk[gc]
                    const int e = gc; int j0, L, s;
                    if (e < 128)      { j0 = 0;  L = 7; s = e; }
                    else if (e < 192) { j0 = 7;  L = 6; s = e - 128; }
                    else              { j0 = 13; L = 6; s = e - 192; }
                    for (int bb = 0; bb < L; ++bb) if ((s >> bb) & 1) v += lin_w[24 + j0 + bb];
                }
                ws[OFF_NO + gr * 256 + gc] = v;
            }
        }
    }
}

// ================= F': pure-gather scoring (~5 lines/row) =================
__global__ __launch_bounds__(256) void ffm_final(const float* __restrict__ ws,
                                                 float* __restrict__ out)
{
    __shared__ float T[LDS_TAB];   // mirrors ws[0..6240): consts | NO | NF | NA
    const int tid = threadIdx.x;
    for (int i = tid; i < LDS_TAB; i += 256) T[i] = ws[i];
    __syncthreads();

    const int row = blockIdx.x * 256 + tid;
    const float    age = ws[OFF_AGE + row];
    const unsigned ca  = reinterpret_cast<const unsigned*>(ws + OFF_CA)[row];
    const unsigned m   = reinterpret_cast<const unsigned*>(ws + OFF_CM)[row];
    const int uid = ca & 1023, iid = (ca >> 10) & 2047, o = (ca >> 21) & 31, g = (ca >> 26) & 1;
    const int c0 = m & 127, c1 = (m >> 7) & 63, c2 = m >> 13;

    const unsigned short* pu = reinterpret_cast<const unsigned short*>(ws + OFF_PUOB) + (size_t)uid * 32;
    const unsigned short* pt = reinterpret_cast<const unsigned short*>(ws + OFF_PTOB) + (size_t)iid * 32;
    const ushort4 qu = *reinterpret_cast<const ushort4*>(pu + 24);  // {au,gu0,gu1,w}
    const ushort4 qt = *reinterpret_cast<const ushort4*>(pt + 24);
    const float ouv = b2f(pu[o]);
    const float otv = b2f(pt[o]);

    const unsigned short* UTb = reinterpret_cast<const unsigned short*>(ws + OFF_UTB);
    const float utv = b2f(UTb[(size_t)uid * 1682 + iid]);

    // movie bit-loop: DMU/DMT rows are single 64B lines -> 1 line each
    const unsigned short* du = reinterpret_cast<const unsigned short*>(ws + OFF_DMUB) + (size_t)uid * 32;
    const unsigned short* dt = reinterpret_cast<const unsigned short*>(ws + OFF_DMTB) + (size_t)iid * 32;
    float mu_acc = 0.f, mt_acc = 0.f;
    unsigned mm = m;
    while (mm) {
        const int j = __builtin_ctz(mm);
        mm &= mm - 1;
        mu_acc += b2f(du[j]);
        mt_acc += b2f(dt[j]);
    }

    const float nov = T[OFF_NO + o * 256 + c0] + T[OFF_NO + o * 256 + 128 + c1] + T[OFF_NO + o * 256 + 192 + c2];
    const float nfv = T[OFF_NF + g * 256 + c0] + T[OFF_NF + g * 256 + 128 + c1] + T[OFF_NF + g * 256 + 192 + c2];
    const float nav = T[OFF_NA + c0] + T[OFF_NA + 128 + c1] + T[OFF_NA + 192 + c2];

    const float total =
          b2f(qu.w) + b2f(qt.w) + T[1]
        + age * T[2] + T[OFF_LWG + g] + T[OFF_LWO + o]
        + age * (T[OFF_AG + g] + T[OFF_AO + o] + b2f(qu.x) + b2f(qt.x))
        + (g ? b2f(qu.z) : b2f(qu.y)) + (g ? b2f(qt.z) : b2f(qt.y))
        + T[OFF_GO + g * 21 + o] + ouv + otv + utv
        + nfv + age * nav + nov + mu_acc + mt_acc;

    out[row] = 1.f / (1.f + __expf(-total));
}

// ---- fallback (round-2 kernel) if ws is too small ----
constexpr int RPW = 16, THREADS = 256, WPB = 4, FPW = RPW * NFEAT;
__global__ __launch_bounds__(THREADS) void ffm_fallback(
    const float* __restrict__ fv,
    const float* __restrict__ AU, const float* __restrict__ AI,
    const float* __restrict__ GU, const float* __restrict__ GI,
    const float* __restrict__ OU, const float* __restrict__ OI,
    const float* __restrict__ MU, const float* __restrict__ MI,
    const float* __restrict__ UU, const float* __restrict__ UI,
    const float* __restrict__ TU, const float* __restrict__ TI,
    const float* __restrict__ user_w, const float* __restrict__ item_w,
    const float* __restrict__ lin_w, const float* __restrict__ lin_b,
    float* __restrict__ out)
{
    __shared__ __align__(16) float stage[WPB][FPW];
    const int lane = threadIdx.x & 63;
    const int wid  = threadIdx.x >> 6;
    const int rowBase = (blockIdx.x * WPB + wid) * RPW;
    {
        const float* src = fv + (size_t)rowBase * NFEAT;
        float* dst = stage[wid];
        #pragma unroll
        for (int t = 0; t < 3; ++t) {
            const int idx = t * 64 + lane;
            if (idx < FPW / 4)
                *reinterpret_cast<float4*>(dst + idx * 4) =
                    *reinterpret_cast<const float4*>(src + idx * 4);
        }
    }
    const float* Srow = stage[wid];
    const float au_w = AU[lane], ai_w = AI[lane];
    const float gu0 = GU[lane], gu1 = GU[64 + lane];
    const float gi0 = GI[lane], gi1 = GI[64 + lane];
    const float lw = (lane >= 2 && lane < NFEAT) ? lin_w[lane - 2] : 0.0f;
    const float bias = lin_b[0];
    float sum_lin = lw;
    #pragma unroll
    for (int off = 32; off; off >>= 1) sum_lin += __shfl_xor(sum_lin, off);
    float myval = 0.0f;
    for (int r = 0; r < RPW; ++r) {
        const float* rp = Srow + r * NFEAT;
        const float x = (lane < NFEAT) ? rp[lane] : 0.0f;
        const int uid = (int)rp[0], iid = (int)rp[1];
        const float age = rp[2], g0 = rp[3], g1 = rp[4];
        const unsigned long long ball = __ballot(x != 0.0f);
        const unsigned occm = (unsigned)((ball >> 5) & 0x1FFFFFull);
        unsigned movm = (unsigned)((ball >> 26) & 0x7FFFFull);
        const float au = age * au_w, ai = age * ai_w;
        const float gu = g0 * gu0 + g1 * gu1, gi = g0 * gi0 + g1 * gi1;
        float ou = 0.0f, oi = 0.0f;
        if (occm) { const int j = __builtin_ctz(occm); ou = OU[j * 64 + lane]; oi = OI[j * 64 + lane]; }
        float mu = 0.0f, mi = 0.0f;
        while (movm) { const int j = __builtin_ctz(movm); movm &= movm - 1; mu += MU[j * 64 + lane]; mi += MI[j * 64 + lane]; }
        const float uu = UU[uid * 64 + lane], ui_ = UI[uid * 64 + lane];
        const float tu = TU[iid * 64 + lane], ti = TI[iid * 64 + lane];
        const float part = (ai + gi + oi) * (mu + tu) + au * (gu + ou + uu)
                         + gu * (ou + uu) + ou * uu + mu * ui_ + mi * ti + ui_ * tu;
        float red = part * sum_lin + x * lw;
        #pragma unroll
        for (int off = 32; off; off >>= 1) red += __shfl_xor(red, off);
        const float val = user_w[uid] + item_w[iid] + bias + red;
        if (lane == r) myval = val;
    }
    if (lane < RPW) out[rowBase + lane] = 1.0f / (1.0f + __expf(-myval));
}

extern "C" void kernel_launch(void* const* d_in, const int* in_sizes, int n_in,
                              void* d_out, int out_size, void* d_ws, size_t ws_size,
                              hipStream_t stream) {
    const float* fv = (const float*)d_in[0];
    const float* AU = (const float*)d_in[1];
    const float* AI = (const float*)d_in[2];
    const float* GU = (const float*)d_in[3];
    const float* GI = (const float*)d_in[4];
    const float* OU = (const float*)d_in[5];
    const float* OI = (const float*)d_in[6];
    const float* MU = (const float*)d_in[7];
    const float* MI = (const float*)d_in[8];
    const float* UU = (const float*)d_in[9];
    const float* UI = (const float*)d_in[10];
    const float* TU = (const float*)d_in[11];
    const float* TI = (const float*)d_in[12];
    const float* uw = (const float*)d_in[13];
    const float* iw = (const float*)d_in[14];
    const float* lw = (const float*)d_in[15];
    const float* lb = (const float*)d_in[16];
    float* out = (float*)d_out;
    float* ws  = (float*)d_ws;

    if (ws_size < TOT_BYTES) {
        ffm_fallback<<<B_ROWS / RPW / WPB, THREADS, 0, stream>>>(
            fv, AU, AI, GU, GI, OU, OI, MU, MI, UU, UI, TU, TI, uw, iw, lw, lb, out);
        return;
    }

    ka2_kernel<<<KA2_BLOCKS, 256, 0, stream>>>(
        fv, AU, AI, GU, GI, OU, OI, MU, MI, UU, UI, TU, TI, uw, iw, lw, lb, ws);
    ffm_final<<<B_ROWS / 256, 256, 0, stream>>>(ws, out);
}